// Round 18
// baseline (623.029 us; speedup 1.0000x reference)
//
#include <hip/hip_runtime.h>
#include <hip/hip_bf16.h>

#define K_NN 32
#define KTOT 33
#define BN_EPS 1e-5f

typedef unsigned int uint32;
typedef unsigned long long ulong64;

__device__ __forceinline__ uint32 key_of_bits(uint32 u) {
    return u ^ ((u & 0x80000000u) ? 0xFFFFFFFFu : 0x80000000u);
}

// ---------------------------------------------------------------- sq norms (layer 1 input only)
template<int F>
__global__ void sqnorm_kernel(const float* __restrict__ x, float* __restrict__ sq, int total) {
    int i = blockIdx.x * blockDim.x + threadIdx.x;
    if (i >= total) return;
    float s = 0.f;
#pragma unroll
    for (int f = 0; f < F; ++f) { float v = x[(size_t)i * F + f]; s += v * v; }
    sq[i] = s;
}

// ---------------------------------------------------------------- symmetric distance matrix, 2 tiles/block
// dist is LDS-byte-bound (2B/FMA at 4x4 blocking vs ~85B/cy/CU supply -> 3x
// oversubscribed). This block computes TWO column-adjacent 64x64 tiles
// (bi,bj0),(bi,bj0+1) sharing one A-panel: 3 ds_read_b128 per 32 FMA =
// 1.5B/FMA (25% less LDS traffic). acc 32 regs, VGPR ~52 (<=64 keeps 8
// waves/SIMD). Grid = (nb, (nb+1)/2, pb); invalid pairs exit uniformly.
// Mirror stores preserve full-D semantics; odd-tail blocks compute a dup
// tile but skip its stores.
template<int F>
__global__ __launch_bounds__(256) void dist_kernel(
        const float* __restrict__ X, const float* __restrict__ sq,
        float* __restrict__ D, int N) {
    constexpr int KD = (F < 32) ? F : 32;
    __shared__ float As[KD][68];
    __shared__ float Bs[2][KD][68];
    const int bz = blockIdx.z;
    const float* Xb  = X  + (size_t)bz * N * F;
    const float* sqb = sq + (size_t)bz * N;
    float* Db = D + (size_t)bz * N * N;

    const int nb = N / 64;
    const int bi  = blockIdx.x;
    const int bj0 = bi + 2 * blockIdx.y;
    if (bj0 >= nb) return;                       // block-uniform exit
    const bool two = (bj0 + 1) < nb;
    const int r0 = bi * 64;
    const int c0 = bj0 * 64;
    const int c1 = two ? (c0 + 64) : c0;         // dup-stage when no 2nd tile

    const int tid = threadIdx.x;
    const int tx = tid & 15, ty = tid >> 4;
    float acc[2][4][4] = {};
    for (int f0 = 0; f0 < F; f0 += KD) {
        __syncthreads();
        if constexpr (KD % 4 == 0) {
            constexpr int QPR = KD / 4;          // float4 quads per row
#pragma unroll
            for (int u = 0; u < (64 * QPR) / 256; ++u) {
                int e = tid + u * 256;
                int r = e / QPR, kq = (e % QPR) * 4;
                float4 va = *(const float4*)&Xb[(size_t)(r0 + r) * F + f0 + kq];
                float4 v0 = *(const float4*)&Xb[(size_t)(c0 + r) * F + f0 + kq];
                float4 v1 = *(const float4*)&Xb[(size_t)(c1 + r) * F + f0 + kq];
                As[kq][r] = va.x; As[kq + 1][r] = va.y; As[kq + 2][r] = va.z; As[kq + 3][r] = va.w;
                Bs[0][kq][r] = v0.x; Bs[0][kq + 1][r] = v0.y; Bs[0][kq + 2][r] = v0.z; Bs[0][kq + 3][r] = v0.w;
                Bs[1][kq][r] = v1.x; Bs[1][kq + 1][r] = v1.y; Bs[1][kq + 2][r] = v1.z; Bs[1][kq + 3][r] = v1.w;
            }
        } else {
            for (int e = tid; e < 64 * KD; e += 256) {
                int r = e / KD, k = e - r * KD;
                As[k][r]    = Xb[(size_t)(r0 + r) * F + f0 + k];
                Bs[0][k][r] = Xb[(size_t)(c0 + r) * F + f0 + k];
                Bs[1][k][r] = Xb[(size_t)(c1 + r) * F + f0 + k];
            }
        }
        __syncthreads();
#pragma unroll
        for (int k = 0; k < KD; ++k) {
            float4 a4 = *(const float4*)&As[k][ty * 4];
            float4 b0 = *(const float4*)&Bs[0][k][tx * 4];
            float4 b1 = *(const float4*)&Bs[1][k][tx * 4];
            const float* a  = (const float*)&a4;
            const float* p0 = (const float*)&b0;
            const float* p1 = (const float*)&b1;
#pragma unroll
            for (int i = 0; i < 4; ++i)
#pragma unroll
                for (int j = 0; j < 4; ++j) {
                    acc[0][i][j] += a[i] * p0[j];
                    acc[1][i][j] += a[i] * p1[j];
                }
        }
    }
    float sr[4];
#pragma unroll
    for (int u = 0; u < 4; ++u) sr[u] = sqb[r0 + ty * 4 + u];

    const int ntile = two ? 2 : 1;
    for (int t = 0; t < ntile; ++t) {
        int cb = c0 + t * 64;
        int bjt = bj0 + t;
        float sc[4];
#pragma unroll
        for (int u = 0; u < 4; ++u) sc[u] = sqb[cb + tx * 4 + u];
        float d4[4][4];
#pragma unroll
        for (int i = 0; i < 4; ++i) {
            int gr = r0 + ty * 4 + i;
            float4 v;
            float* vp = (float*)&v;
#pragma unroll
            for (int j = 0; j < 4; ++j) {
                int gc = cb + tx * 4 + j;
                float d = sr[i] + sc[j] - 2.f * acc[t][i][j];
                if (gr == gc) d = 1e30f;
                d4[i][j] = d;
                vp[j] = d;
            }
            *(float4*)&Db[(size_t)gr * N + cb + tx * 4] = v;
        }
        if (bjt != bi) {
#pragma unroll
            for (int j = 0; j < 4; ++j) {
                int gc = cb + tx * 4 + j;
                float4 v = make_float4(d4[0][j], d4[1][j], d4[2][j], d4[3][j]);
                *(float4*)&Db[(size_t)gc * N + r0 + ty * 4] = v;
            }
        }
    }
}

// ---------------------------------------------------------------- wave-synchronous radix top-32
// R17 verbatim (measured best): keys in registers; pass 1 = iterative
// wave-min; passes 2-4 = 4-replica rep-major padded histogram; lane-local
// less-collection + independent-ballot eq-collection (smallest-index
// tie-break preserved).
template<int N>
__global__ __launch_bounds__(256) void knn_select_kernel(
        const float* __restrict__ D, int* __restrict__ idx_out, int b0) {
    constexpr int CH = N / 64;                 // keys per lane
    constexpr int HW = 4 * 264;                // words per wave (4 reps, padded)
    __shared__ int hist[4][HW];
    int wv = threadIdx.x >> 6;
    int ln = threadIdx.x & 63;
    int rep = (ln >> 4) & 3;
    int row = blockIdx.x * 4 + wv;
    int b   = b0 + row / N;
    int i   = row & (N - 1);
    const uint32* drow = (const uint32*)(D + (size_t)row * N);
    int* hw = hist[wv];

    uint32 kreg[CH];
#pragma unroll
    for (int c = 0; c < CH; ++c) kreg[c] = key_of_bits(drow[c * 64 + ln]);

    uint32 prefix = 0;
    int need = K_NN;

    // ---- pass 1 (bits 31:24): iterative wave-min + count, no LDS
    {
        int vprev = -1, cum = 0, chosen = 0, fex = 0;
        while (true) {
            int lm = 256;
#pragma unroll
            for (int c = 0; c < CH; ++c) {
                int bc = (int)(kreg[c] >> 24);
                lm = (bc > vprev && bc < lm) ? bc : lm;
            }
#pragma unroll
            for (int off = 32; off > 0; off >>= 1) {
                int o = __shfl_xor(lm, off, 64);
                lm = (o < lm) ? o : lm;
            }
            int lc = 0;
#pragma unroll
            for (int c = 0; c < CH; ++c) lc += ((int)(kreg[c] >> 24) == lm);
#pragma unroll
            for (int off = 32; off > 0; off >>= 1) lc += __shfl_xor(lc, off, 64);
            if (cum + lc >= need) { chosen = lm; fex = cum; break; }
            cum += lc; vprev = lm;
        }
        prefix = ((uint32)chosen) << 24;
        need -= fex;
    }

    // ---- passes 2-4: replicated padded histogram
#pragma unroll
    for (int shift = 16; shift >= 0; shift -= 8) {
#pragma unroll
        for (int u = 0; u < (HW + 63) / 64; ++u) {
            int w = u * 64 + ln;
            if (w < HW) hw[w] = 0;
        }
        uint32 himask = (uint32)(~((1ull << (shift + 8)) - 1ull));
#pragma unroll
        for (int c = 0; c < CH; ++c) {
            uint32 k = kreg[c];
            if (((k ^ prefix) & himask) == 0) {
                int bin = (int)((k >> shift) & 255u);
                atomicAdd(&hw[rep * 264 + bin + (bin >> 5)], 1);
            }
        }
        int hh[4];
#pragma unroll
        for (int u = 0; u < 4; ++u) {
            int bin = 4 * ln + u;
            int bb = bin + (bin >> 5);
            hh[u] = hw[bb] + hw[264 + bb] + hw[528 + bb] + hw[792 + bb];
        }
        int s0 = hh[0], s1 = s0 + hh[1], s2 = s1 + hh[2], s3 = s2 + hh[3];
        int run = s3;
#pragma unroll
        for (int off = 1; off < 64; off <<= 1) {
            int v = __shfl_up(run, off, 64);
            if (ln >= off) run += v;
        }
        int ex = run - s3;
        int fbin = -1, fex = 0;
        if      (ex      < need && ex + s0 >= need) { fbin = 4 * ln;     fex = ex; }
        else if (ex + s0 < need && ex + s1 >= need) { fbin = 4 * ln + 1; fex = ex + s0; }
        else if (ex + s1 < need && ex + s2 >= need) { fbin = 4 * ln + 2; fex = ex + s1; }
        else if (ex + s2 < need && ex + s3 >= need) { fbin = 4 * ln + 3; fex = ex + s2; }
        ulong64 bm = __ballot(fbin >= 0);
        int srcl = __ffsll((long long)bm) - 1;
        int bin  = __shfl(fbin, srcl, 64);
        int bex  = __shfl(fex,  srcl, 64);
        prefix |= ((uint32)bin) << shift;
        need -= bex;
    }
    int cl = K_NN - need;
    int gbase = b * N;
    int* op = idx_out + (size_t)(gbase + i) * KTOT;
    ulong64 lom = (1ull << ln) - 1ull;

    int lcnt = 0;
#pragma unroll
    for (int c = 0; c < CH; ++c) lcnt += (kreg[c] < prefix) ? 1 : 0;
    int scan = lcnt;
#pragma unroll
    for (int off = 1; off < 64; off <<= 1) {
        int v = __shfl_up(scan, off, 64);
        if (ln >= off) scan += v;
    }
    int wbase = scan - lcnt;
#pragma unroll
    for (int c = 0; c < CH; ++c) {
        if (kreg[c] < prefix) { op[wbase] = gbase + c * 64 + ln; ++wbase; }
    }

    {
        int ec[CH];
#pragma unroll
        for (int c = 0; c < CH; ++c) {
            ulong64 be = __ballot(kreg[c] == prefix);
            ec[c] = (__popcll(be) << 8) | __popcll(be & lom);
        }
        int pe = 0;
#pragma unroll
        for (int c = 0; c < CH; ++c) {
            int cnt  = ec[c] >> 8;
            int rank = ec[c] & 255;
            if (kreg[c] == prefix) {
                int slot = cl + pe + rank;
                if (slot < K_NN) op[slot] = gbase + c * 64 + ln;
            }
            pe += cnt;
        }
    }
    if (ln == 0) op[K_NN] = gbase + i;
}

// ---------------------------------------------------------------- linear
template<int IN, int OUT>
__global__ void linear_kernel(const float* __restrict__ x, const float* __restrict__ W,
                              float* __restrict__ y, int total) {
    int t = blockIdx.x * blockDim.x + threadIdx.x;
    if (t >= total * OUT) return;
    int o = t % OUT;
    int i = t / OUT;
    float a0 = 0.f, a1 = 0.f, a2 = 0.f, a3 = 0.f;
#pragma unroll
    for (int f = 0; f + 3 < IN; f += 4) {
        a0 += x[(size_t)i * IN + f]     * W[(f) * OUT + o];
        a1 += x[(size_t)i * IN + f + 1] * W[(f + 1) * OUT + o];
        a2 += x[(size_t)i * IN + f + 2] * W[(f + 2) * OUT + o];
        a3 += x[(size_t)i * IN + f + 3] * W[(f + 3) * OUT + o];
    }
#pragma unroll
    for (int f = IN & ~3; f < IN; ++f) a0 += x[(size_t)i * IN + f] * W[f * OUT + o];
    y[t] = (a0 + a1) + (a2 + a3);
}

// ---------------------------------------------------------------- scores
template<int H, int C>
__global__ void scores_kernel(const float* __restrict__ xw, const float* __restrict__ att,
                              float* __restrict__ sd, float* __restrict__ ss, int total) {
    int t = blockIdx.x * blockDim.x + threadIdx.x;
    if (t >= total * H) return;
    int h = t % H;
    int i = t / H;
    float d = 0.f, s = 0.f;
#pragma unroll
    for (int c = 0; c < C; ++c) {
        float v = xw[(size_t)i * H * C + h * C + c];
        d += v * att[h * 2 * C + c];
        s += v * att[h * 2 * C + C + c];
    }
    sd[t] = d;
    ss[t] = s;
}

// ---------------------------------------------------------------- gat gather
template<int H, int C>
__global__ __launch_bounds__(256) void gat_kernel(
        const float* __restrict__ xw, const float* __restrict__ sd,
        const float* __restrict__ ss, const int* __restrict__ idx,
        const float* __restrict__ bias, const float* __restrict__ prelu,
        float slope, float* __restrict__ out, int total) {
    constexpr int HC = H * C;
    constexpr int WPN = (HC + 63) / 64;
    int gw = (int)((blockIdx.x * (size_t)blockDim.x + threadIdx.x) >> 6);
    int ln = threadIdx.x & 63;
    int i  = gw / WPN;
    int wsub = gw - i * WPN;
    if (i >= total) return;
    int ch = wsub * 64 + ln;
    bool act = ch < HC;
    int h = act ? (ch / C) : 0;
    const int* ip = idx + (size_t)i * KTOT;
    int jl = (ln < KTOT) ? ip[ln] : 0;
    float sdi = act ? sd[(size_t)i * H + h] : 0.f;
    float m = -1e30f, l = 0.f, acc = 0.f;
    for (int k = 0; k < KTOT; ++k) {
        int j = __shfl(jl, k, 64);
        float e = sdi + (act ? ss[(size_t)j * H + h] : 0.f);
        e = (e >= 0.f) ? e : slope * e;
        float mn = fmaxf(m, e);
        float scl = __expf(m - mn);
        float w   = __expf(e - mn);
        l = l * scl + w;
        float xv = act ? xw[(size_t)j * HC + ch] : 0.f;
        acc = acc * scl + w * xv;
        m = mn;
    }
    if (act) {
        float r = acc / l;
        if (bias) r += bias[ch];
        if (prelu) { float p0 = prelu[0]; r = (r >= 0.f) ? r : p0 * r; }
        out[(size_t)i * HC + ch] = r;
    }
}

// ---------------------------------------------------------------- bn partial sums (coalesced)
template<int C>
__global__ __launch_bounds__(256) void bn_partial_kernel(
        const float* __restrict__ h, float* __restrict__ part, int rows, int nblk) {
    constexpr int RPT = 256 / C;
    int c  = threadIdx.x & (C - 1);
    int rs = threadIdx.x / C;
    int rpb = (rows + nblk - 1) / nblk;
    int r0 = blockIdx.x * rpb;
    int r1 = r0 + rpb; if (r1 > rows) r1 = rows;
    float s = 0.f, s2 = 0.f;
    for (int r = r0 + rs; r < r1; r += RPT) {
        float v = h[(size_t)r * C + c];
        s += v; s2 += v * v;
    }
    __shared__ float ls[2][256];
    ls[0][threadIdx.x] = s; ls[1][threadIdx.x] = s2;
    __syncthreads();
    if (rs == 0) {
#pragma unroll
        for (int g = 1; g < RPT; ++g) { s += ls[0][g * C + c]; s2 += ls[1][g * C + c]; }
        part[(size_t)blockIdx.x * 2 * C + c]     = s;
        part[(size_t)blockIdx.x * 2 * C + C + c] = s2;
    }
}

template<int C>
__global__ void bn_finalize_kernel(const float* __restrict__ part, float* __restrict__ stats,
                                   int nblk, int rows) {
    int c = threadIdx.x;
    float s = 0.f, s2 = 0.f;
    for (int p = 0; p < nblk; ++p) {
        s  += part[(size_t)p * 2 * C + c];
        s2 += part[(size_t)p * 2 * C + C + c];
    }
    float mean = s / rows;
    float var  = s2 / rows - mean * mean;
    stats[c * 2]     = mean;
    stats[c * 2 + 1] = rsqrtf(var + BN_EPS);
}

// ---------------------------------------------------------------- bn apply + next-layer sqnorm
template<int C>
__global__ __launch_bounds__(256) void bn_apply_sq_kernel(
        float* __restrict__ h, const float* __restrict__ stats,
        const float* __restrict__ g, const float* __restrict__ be,
        float* __restrict__ sq, int total) {
    constexpr int VPL = C / 64;
    int gw = (int)((blockIdx.x * (size_t)blockDim.x + threadIdx.x) >> 6);
    int ln = threadIdx.x & 63;
    if (gw >= total) return;
    float ssum = 0.f;
#pragma unroll
    for (int u = 0; u < VPL; ++u) {
        int c = u * 64 + ln;
        float v = h[(size_t)gw * C + c];
        v = (v - stats[c * 2]) * stats[c * 2 + 1] * g[c] + be[c];
        h[(size_t)gw * C + c] = v;
        ssum += v * v;
    }
#pragma unroll
    for (int off = 32; off > 0; off >>= 1) ssum += __shfl_down(ssum, off, 64);
    if (ln == 0) sq[gw] = ssum;
}

// ---------------------------------------------------------------- final
__global__ void final_kernel(const float* __restrict__ g3, const float* __restrict__ b3,
                             const float* __restrict__ Wc, const float* __restrict__ bc,
                             float* __restrict__ out, int total) {
    int t = blockIdx.x * blockDim.x + threadIdx.x;
    if (t >= total * 16) return;
    int o = t & 15;
    int i = t >> 4;
    float acc = bc[o];
#pragma unroll
    for (int c = 0; c < 6; ++c) {
        float hm = 0.f;
#pragma unroll
        for (int h = 0; h < 8; ++h) hm += g3[(size_t)i * 48 + h * 6 + c];
        hm = hm * 0.125f + b3[c];
        acc += hm * Wc[c * 16 + o];
    }
    out[t] = acc;
}

static inline int cdiv(int a, int b) { return (a + b - 1) / b; }

extern "C" void kernel_launch(void* const* d_in, const int* in_sizes, int n_in,
                              void* d_out, int out_size, void* d_ws, size_t ws_size,
                              hipStream_t stream) {
    const float* x    = (const float*)d_in[0];
    const float* W1   = (const float*)d_in[2];
    const float* att1 = (const float*)d_in[3];
    const float* b1   = (const float*)d_in[4];
    const float* p1   = (const float*)d_in[5];
    const float* g1   = (const float*)d_in[6];
    const float* be1  = (const float*)d_in[7];
    const float* W2   = (const float*)d_in[8];
    const float* att2 = (const float*)d_in[9];
    const float* b2   = (const float*)d_in[10];
    const float* p2   = (const float*)d_in[11];
    const float* g2   = (const float*)d_in[12];
    const float* be2  = (const float*)d_in[13];
    const float* W3   = (const float*)d_in[14];
    const float* att3 = (const float*)d_in[15];
    const float* b3   = (const float*)d_in[16];
    const float* Wc   = (const float*)d_in[17];
    const float* bc   = (const float*)d_in[18];

    const int B = 8, N = 2048, T = B * N;
    const int NBLK = 256;
    (void)n_in; (void)in_sizes; (void)out_size;

    float* ws    = (float*)d_ws;
    float* bufA  = ws;                            // T*64
    float* bufB  = bufA + (size_t)T * 64;         // T*128
    float* bufC  = bufB + (size_t)T * 128;        // T*48
    float* sd    = bufC + (size_t)T * 48;         // T*8
    float* ss    = sd   + (size_t)T * 8;          // T*8
    float* sq    = ss   + (size_t)T * 8;          // T
    float* stats = sq   + T;                      // 256
    float* part  = stats + 256;                   // NBLK*2*128
    int*   idx   = (int*)(part + (size_t)NBLK * 256); // T*33
    float* Dxw   = (float*)(idx + (size_t)T * KTOT);  // max(T*128, PB*N*N)
    float* xw    = Dxw;

    size_t fixed_words = (size_t)(Dxw - ws);
    size_t avail_words = (ws_size / 4 > fixed_words) ? (ws_size / 4 - fixed_words) : 0;
    int PB = (int)(avail_words / ((size_t)N * N));
    if (PB < 1) PB = 1;
    if (PB > B) PB = B;

    const int BS = 256;
    const int nb = N / 64;
    const dim3 dgrid0(nb, (nb + 1) / 2, 1);

    // ================= Layer 1 (F=3 -> H=4,C=16 -> 64) =================
    sqnorm_kernel<3><<<cdiv(T, BS), BS, 0, stream>>>(x, sq, T);
    for (int b0 = 0; b0 < B; b0 += PB) {
        int pb = (b0 + PB <= B) ? PB : (B - b0);
        dist_kernel<3><<<dim3(nb, (nb + 1) / 2, pb), 256, 0, stream>>>(
            x + (size_t)b0 * N * 3, sq + (size_t)b0 * N, Dxw, N);
        knn_select_kernel<2048><<<pb * N / 4, 256, 0, stream>>>(Dxw, idx, b0);
    }
    linear_kernel<3, 64><<<cdiv(T * 64, BS), BS, 0, stream>>>(x, W1, xw, T);
    scores_kernel<4, 16><<<cdiv(T * 4, BS), BS, 0, stream>>>(xw, att1, sd, ss, T);
    gat_kernel<4, 16><<<cdiv(T * 64, BS), BS, 0, stream>>>(xw, sd, ss, idx, b1, p1, 0.2f, bufA, T);
    bn_partial_kernel<64><<<NBLK, 256, 0, stream>>>(bufA, part, T, NBLK);
    bn_finalize_kernel<64><<<1, 64, 0, stream>>>(part, stats, NBLK, T);
    bn_apply_sq_kernel<64><<<cdiv(T, 4), 256, 0, stream>>>(bufA, stats, g1, be1, sq, T);

    // ================= Layer 2 (F=64 -> H=2,C=64 -> 128) =================
    for (int b0 = 0; b0 < B; b0 += PB) {
        int pb = (b0 + PB <= B) ? PB : (B - b0);
        dist_kernel<64><<<dim3(nb, (nb + 1) / 2, pb), 256, 0, stream>>>(
            bufA + (size_t)b0 * N * 64, sq + (size_t)b0 * N, Dxw, N);
        knn_select_kernel<2048><<<pb * N / 4, 256, 0, stream>>>(Dxw, idx, b0);
    }
    linear_kernel<64, 128><<<cdiv(T * 128, BS), BS, 0, stream>>>(bufA, W2, xw, T);
    scores_kernel<2, 64><<<cdiv(T * 2, BS), BS, 0, stream>>>(xw, att2, sd, ss, T);
    gat_kernel<2, 64><<<cdiv(T * 2 * 64, BS), BS, 0, stream>>>(xw, sd, ss, idx, b2, p2, 0.2f, bufB, T);
    bn_partial_kernel<128><<<NBLK, 256, 0, stream>>>(bufB, part, T, NBLK);
    bn_finalize_kernel<128><<<1, 128, 0, stream>>>(part, stats, NBLK, T);
    bn_apply_sq_kernel<128><<<cdiv(T, 4), 256, 0, stream>>>(bufB, stats, g2, be2, sq, T);

    // ================= Layer 3 (F=128 -> H=8,C=6 -> mean -> 6) =================
    for (int b0 = 0; b0 < B; b0 += PB) {
        int pb = (b0 + PB <= B) ? PB : (B - b0);
        dist_kernel<128><<<dim3(nb, (nb + 1) / 2, pb), 256, 0, stream>>>(
            bufB + (size_t)b0 * N * 128, sq + (size_t)b0 * N, Dxw, N);
        knn_select_kernel<2048><<<pb * N / 4, 256, 0, stream>>>(Dxw, idx, b0);
    }
    linear_kernel<128, 48><<<cdiv(T * 48, BS), BS, 0, stream>>>(bufB, W3, xw, T);
    scores_kernel<8, 6><<<cdiv(T * 8, BS), BS, 0, stream>>>(xw, att3, sd, ss, T);
    gat_kernel<8, 6><<<cdiv(T * 64, BS), BS, 0, stream>>>(xw, sd, ss, idx, nullptr, nullptr, 0.5f, bufC, T);

    // ================= Final =================
    final_kernel<<<cdiv(T * 16, BS), BS, 0, stream>>>(bufC, b3, Wc, bc, (float*)d_out, T);
}

// Round 19
// 614.833 us; speedup vs baseline: 1.0133x; 1.0133x over previous
//
#include <hip/hip_runtime.h>
#include <hip/hip_bf16.h>

#define K_NN 32
#define KTOT 33
#define BN_EPS 1e-5f

typedef unsigned int uint32;
typedef unsigned long long ulong64;

__device__ __forceinline__ uint32 key_of_bits(uint32 u) {
    return u ^ ((u & 0x80000000u) ? 0xFFFFFFFFu : 0x80000000u);
}

// ---------------------------------------------------------------- sq norms (layer 1 input only)
template<int F>
__global__ void sqnorm_kernel(const float* __restrict__ x, float* __restrict__ sq, int total) {
    int i = blockIdx.x * blockDim.x + threadIdx.x;
    if (i >= total) return;
    float s = 0.f;
#pragma unroll
    for (int f = 0; f < F; ++f) { float v = x[(size_t)i * F + f]; s += v * v; }
    sq[i] = s;
}

// ---------------------------------------------------------------- symmetric distance matrix, 2 tiles/block
// 2 column-adjacent tiles share one A-panel: 3 ds_read_b128 per 32 FMA
// (1.5B/FMA, 25% less LDS traffic than single-tile). R18 lesson: KD=32 made
// LDS 26KB and occupancy collapsed to 25% (2 blocks/CU). KD=16 -> LDS 13KB,
// blocks/CU ceiling >= R17's 17.4KB config, at the cost of 2x staging
// barriers (R11 measured that penalty as small).
template<int F>
__global__ __launch_bounds__(256) void dist_kernel(
        const float* __restrict__ X, const float* __restrict__ sq,
        float* __restrict__ D, int N) {
    constexpr int KD = (F < 16) ? F : 16;
    __shared__ float As[KD][68];
    __shared__ float Bs[2][KD][68];
    const int bz = blockIdx.z;
    const float* Xb  = X  + (size_t)bz * N * F;
    const float* sqb = sq + (size_t)bz * N;
    float* Db = D + (size_t)bz * N * N;

    const int nb = N / 64;
    const int bi  = blockIdx.x;
    const int bj0 = bi + 2 * blockIdx.y;
    if (bj0 >= nb) return;                       // block-uniform exit
    const bool two = (bj0 + 1) < nb;
    const int r0 = bi * 64;
    const int c0 = bj0 * 64;
    const int c1 = two ? (c0 + 64) : c0;         // dup-stage when no 2nd tile

    const int tid = threadIdx.x;
    const int tx = tid & 15, ty = tid >> 4;
    float acc[2][4][4] = {};
    for (int f0 = 0; f0 < F; f0 += KD) {
        __syncthreads();
        if constexpr (KD % 4 == 0) {
            constexpr int QPR = KD / 4;          // float4 quads per row
#pragma unroll
            for (int u = 0; u < (64 * QPR) / 256; ++u) {
                int e = tid + u * 256;
                int r = e / QPR, kq = (e % QPR) * 4;
                float4 va = *(const float4*)&Xb[(size_t)(r0 + r) * F + f0 + kq];
                float4 v0 = *(const float4*)&Xb[(size_t)(c0 + r) * F + f0 + kq];
                float4 v1 = *(const float4*)&Xb[(size_t)(c1 + r) * F + f0 + kq];
                As[kq][r] = va.x; As[kq + 1][r] = va.y; As[kq + 2][r] = va.z; As[kq + 3][r] = va.w;
                Bs[0][kq][r] = v0.x; Bs[0][kq + 1][r] = v0.y; Bs[0][kq + 2][r] = v0.z; Bs[0][kq + 3][r] = v0.w;
                Bs[1][kq][r] = v1.x; Bs[1][kq + 1][r] = v1.y; Bs[1][kq + 2][r] = v1.z; Bs[1][kq + 3][r] = v1.w;
            }
        } else {
            for (int e = tid; e < 64 * KD; e += 256) {
                int r = e / KD, k = e - r * KD;
                As[k][r]    = Xb[(size_t)(r0 + r) * F + f0 + k];
                Bs[0][k][r] = Xb[(size_t)(c0 + r) * F + f0 + k];
                Bs[1][k][r] = Xb[(size_t)(c1 + r) * F + f0 + k];
            }
        }
        __syncthreads();
#pragma unroll
        for (int k = 0; k < KD; ++k) {
            float4 a4 = *(const float4*)&As[k][ty * 4];
            float4 b0 = *(const float4*)&Bs[0][k][tx * 4];
            float4 b1 = *(const float4*)&Bs[1][k][tx * 4];
            const float* a  = (const float*)&a4;
            const float* p0 = (const float*)&b0;
            const float* p1 = (const float*)&b1;
#pragma unroll
            for (int i = 0; i < 4; ++i)
#pragma unroll
                for (int j = 0; j < 4; ++j) {
                    acc[0][i][j] += a[i] * p0[j];
                    acc[1][i][j] += a[i] * p1[j];
                }
        }
    }
    float sr[4];
#pragma unroll
    for (int u = 0; u < 4; ++u) sr[u] = sqb[r0 + ty * 4 + u];

    const int ntile = two ? 2 : 1;
    for (int t = 0; t < ntile; ++t) {
        int cb = c0 + t * 64;
        int bjt = bj0 + t;
        float sc[4];
#pragma unroll
        for (int u = 0; u < 4; ++u) sc[u] = sqb[cb + tx * 4 + u];
        float d4[4][4];
#pragma unroll
        for (int i = 0; i < 4; ++i) {
            int gr = r0 + ty * 4 + i;
            float4 v;
            float* vp = (float*)&v;
#pragma unroll
            for (int j = 0; j < 4; ++j) {
                int gc = cb + tx * 4 + j;
                float d = sr[i] + sc[j] - 2.f * acc[t][i][j];
                if (gr == gc) d = 1e30f;
                d4[i][j] = d;
                vp[j] = d;
            }
            *(float4*)&Db[(size_t)gr * N + cb + tx * 4] = v;
        }
        if (bjt != bi) {
#pragma unroll
            for (int j = 0; j < 4; ++j) {
                int gc = cb + tx * 4 + j;
                float4 v = make_float4(d4[0][j], d4[1][j], d4[2][j], d4[3][j]);
                *(float4*)&Db[(size_t)gc * N + r0 + ty * 4] = v;
            }
        }
    }
}

// ---------------------------------------------------------------- wave-synchronous radix top-32
// R17 verbatim (measured best): keys in registers; pass 1 = iterative
// wave-min; passes 2-4 = 4-replica rep-major padded histogram; lane-local
// less-collection + independent-ballot eq-collection (smallest-index
// tie-break preserved).
template<int N>
__global__ __launch_bounds__(256) void knn_select_kernel(
        const float* __restrict__ D, int* __restrict__ idx_out, int b0) {
    constexpr int CH = N / 64;                 // keys per lane
    constexpr int HW = 4 * 264;                // words per wave (4 reps, padded)
    __shared__ int hist[4][HW];
    int wv = threadIdx.x >> 6;
    int ln = threadIdx.x & 63;
    int rep = (ln >> 4) & 3;
    int row = blockIdx.x * 4 + wv;
    int b   = b0 + row / N;
    int i   = row & (N - 1);
    const uint32* drow = (const uint32*)(D + (size_t)row * N);
    int* hw = hist[wv];

    uint32 kreg[CH];
#pragma unroll
    for (int c = 0; c < CH; ++c) kreg[c] = key_of_bits(drow[c * 64 + ln]);

    uint32 prefix = 0;
    int need = K_NN;

    // ---- pass 1 (bits 31:24): iterative wave-min + count, no LDS
    {
        int vprev = -1, cum = 0, chosen = 0, fex = 0;
        while (true) {
            int lm = 256;
#pragma unroll
            for (int c = 0; c < CH; ++c) {
                int bc = (int)(kreg[c] >> 24);
                lm = (bc > vprev && bc < lm) ? bc : lm;
            }
#pragma unroll
            for (int off = 32; off > 0; off >>= 1) {
                int o = __shfl_xor(lm, off, 64);
                lm = (o < lm) ? o : lm;
            }
            int lc = 0;
#pragma unroll
            for (int c = 0; c < CH; ++c) lc += ((int)(kreg[c] >> 24) == lm);
#pragma unroll
            for (int off = 32; off > 0; off >>= 1) lc += __shfl_xor(lc, off, 64);
            if (cum + lc >= need) { chosen = lm; fex = cum; break; }
            cum += lc; vprev = lm;
        }
        prefix = ((uint32)chosen) << 24;
        need -= fex;
    }

    // ---- passes 2-4: replicated padded histogram
#pragma unroll
    for (int shift = 16; shift >= 0; shift -= 8) {
#pragma unroll
        for (int u = 0; u < (HW + 63) / 64; ++u) {
            int w = u * 64 + ln;
            if (w < HW) hw[w] = 0;
        }
        uint32 himask = (uint32)(~((1ull << (shift + 8)) - 1ull));
#pragma unroll
        for (int c = 0; c < CH; ++c) {
            uint32 k = kreg[c];
            if (((k ^ prefix) & himask) == 0) {
                int bin = (int)((k >> shift) & 255u);
                atomicAdd(&hw[rep * 264 + bin + (bin >> 5)], 1);
            }
        }
        int hh[4];
#pragma unroll
        for (int u = 0; u < 4; ++u) {
            int bin = 4 * ln + u;
            int bb = bin + (bin >> 5);
            hh[u] = hw[bb] + hw[264 + bb] + hw[528 + bb] + hw[792 + bb];
        }
        int s0 = hh[0], s1 = s0 + hh[1], s2 = s1 + hh[2], s3 = s2 + hh[3];
        int run = s3;
#pragma unroll
        for (int off = 1; off < 64; off <<= 1) {
            int v = __shfl_up(run, off, 64);
            if (ln >= off) run += v;
        }
        int ex = run - s3;
        int fbin = -1, fex = 0;
        if      (ex      < need && ex + s0 >= need) { fbin = 4 * ln;     fex = ex; }
        else if (ex + s0 < need && ex + s1 >= need) { fbin = 4 * ln + 1; fex = ex + s0; }
        else if (ex + s1 < need && ex + s2 >= need) { fbin = 4 * ln + 2; fex = ex + s1; }
        else if (ex + s2 < need && ex + s3 >= need) { fbin = 4 * ln + 3; fex = ex + s2; }
        ulong64 bm = __ballot(fbin >= 0);
        int srcl = __ffsll((long long)bm) - 1;
        int bin  = __shfl(fbin, srcl, 64);
        int bex  = __shfl(fex,  srcl, 64);
        prefix |= ((uint32)bin) << shift;
        need -= bex;
    }
    int cl = K_NN - need;
    int gbase = b * N;
    int* op = idx_out + (size_t)(gbase + i) * KTOT;
    ulong64 lom = (1ull << ln) - 1ull;

    int lcnt = 0;
#pragma unroll
    for (int c = 0; c < CH; ++c) lcnt += (kreg[c] < prefix) ? 1 : 0;
    int scan = lcnt;
#pragma unroll
    for (int off = 1; off < 64; off <<= 1) {
        int v = __shfl_up(scan, off, 64);
        if (ln >= off) scan += v;
    }
    int wbase = scan - lcnt;
#pragma unroll
    for (int c = 0; c < CH; ++c) {
        if (kreg[c] < prefix) { op[wbase] = gbase + c * 64 + ln; ++wbase; }
    }

    {
        int ec[CH];
#pragma unroll
        for (int c = 0; c < CH; ++c) {
            ulong64 be = __ballot(kreg[c] == prefix);
            ec[c] = (__popcll(be) << 8) | __popcll(be & lom);
        }
        int pe = 0;
#pragma unroll
        for (int c = 0; c < CH; ++c) {
            int cnt  = ec[c] >> 8;
            int rank = ec[c] & 255;
            if (kreg[c] == prefix) {
                int slot = cl + pe + rank;
                if (slot < K_NN) op[slot] = gbase + c * 64 + ln;
            }
            pe += cnt;
        }
    }
    if (ln == 0) op[K_NN] = gbase + i;
}

// ---------------------------------------------------------------- linear
template<int IN, int OUT>
__global__ void linear_kernel(const float* __restrict__ x, const float* __restrict__ W,
                              float* __restrict__ y, int total) {
    int t = blockIdx.x * blockDim.x + threadIdx.x;
    if (t >= total * OUT) return;
    int o = t % OUT;
    int i = t / OUT;
    float a0 = 0.f, a1 = 0.f, a2 = 0.f, a3 = 0.f;
#pragma unroll
    for (int f = 0; f + 3 < IN; f += 4) {
        a0 += x[(size_t)i * IN + f]     * W[(f) * OUT + o];
        a1 += x[(size_t)i * IN + f + 1] * W[(f + 1) * OUT + o];
        a2 += x[(size_t)i * IN + f + 2] * W[(f + 2) * OUT + o];
        a3 += x[(size_t)i * IN + f + 3] * W[(f + 3) * OUT + o];
    }
#pragma unroll
    for (int f = IN & ~3; f < IN; ++f) a0 += x[(size_t)i * IN + f] * W[f * OUT + o];
    y[t] = (a0 + a1) + (a2 + a3);
}

// ---------------------------------------------------------------- scores
template<int H, int C>
__global__ void scores_kernel(const float* __restrict__ xw, const float* __restrict__ att,
                              float* __restrict__ sd, float* __restrict__ ss, int total) {
    int t = blockIdx.x * blockDim.x + threadIdx.x;
    if (t >= total * H) return;
    int h = t % H;
    int i = t / H;
    float d = 0.f, s = 0.f;
#pragma unroll
    for (int c = 0; c < C; ++c) {
        float v = xw[(size_t)i * H * C + h * C + c];
        d += v * att[h * 2 * C + c];
        s += v * att[h * 2 * C + C + c];
    }
    sd[t] = d;
    ss[t] = s;
}

// ---------------------------------------------------------------- gat gather
template<int H, int C>
__global__ __launch_bounds__(256) void gat_kernel(
        const float* __restrict__ xw, const float* __restrict__ sd,
        const float* __restrict__ ss, const int* __restrict__ idx,
        const float* __restrict__ bias, const float* __restrict__ prelu,
        float slope, float* __restrict__ out, int total) {
    constexpr int HC = H * C;
    constexpr int WPN = (HC + 63) / 64;
    int gw = (int)((blockIdx.x * (size_t)blockDim.x + threadIdx.x) >> 6);
    int ln = threadIdx.x & 63;
    int i  = gw / WPN;
    int wsub = gw - i * WPN;
    if (i >= total) return;
    int ch = wsub * 64 + ln;
    bool act = ch < HC;
    int h = act ? (ch / C) : 0;
    const int* ip = idx + (size_t)i * KTOT;
    int jl = (ln < KTOT) ? ip[ln] : 0;
    float sdi = act ? sd[(size_t)i * H + h] : 0.f;
    float m = -1e30f, l = 0.f, acc = 0.f;
    for (int k = 0; k < KTOT; ++k) {
        int j = __shfl(jl, k, 64);
        float e = sdi + (act ? ss[(size_t)j * H + h] : 0.f);
        e = (e >= 0.f) ? e : slope * e;
        float mn = fmaxf(m, e);
        float scl = __expf(m - mn);
        float w   = __expf(e - mn);
        l = l * scl + w;
        float xv = act ? xw[(size_t)j * HC + ch] : 0.f;
        acc = acc * scl + w * xv;
        m = mn;
    }
    if (act) {
        float r = acc / l;
        if (bias) r += bias[ch];
        if (prelu) { float p0 = prelu[0]; r = (r >= 0.f) ? r : p0 * r; }
        out[(size_t)i * HC + ch] = r;
    }
}

// ---------------------------------------------------------------- bn partial sums (coalesced)
template<int C>
__global__ __launch_bounds__(256) void bn_partial_kernel(
        const float* __restrict__ h, float* __restrict__ part, int rows, int nblk) {
    constexpr int RPT = 256 / C;
    int c  = threadIdx.x & (C - 1);
    int rs = threadIdx.x / C;
    int rpb = (rows + nblk - 1) / nblk;
    int r0 = blockIdx.x * rpb;
    int r1 = r0 + rpb; if (r1 > rows) r1 = rows;
    float s = 0.f, s2 = 0.f;
    for (int r = r0 + rs; r < r1; r += RPT) {
        float v = h[(size_t)r * C + c];
        s += v; s2 += v * v;
    }
    __shared__ float ls[2][256];
    ls[0][threadIdx.x] = s; ls[1][threadIdx.x] = s2;
    __syncthreads();
    if (rs == 0) {
#pragma unroll
        for (int g = 1; g < RPT; ++g) { s += ls[0][g * C + c]; s2 += ls[1][g * C + c]; }
        part[(size_t)blockIdx.x * 2 * C + c]     = s;
        part[(size_t)blockIdx.x * 2 * C + C + c] = s2;
    }
}

template<int C>
__global__ void bn_finalize_kernel(const float* __restrict__ part, float* __restrict__ stats,
                                   int nblk, int rows) {
    int c = threadIdx.x;
    float s = 0.f, s2 = 0.f;
    for (int p = 0; p < nblk; ++p) {
        s  += part[(size_t)p * 2 * C + c];
        s2 += part[(size_t)p * 2 * C + C + c];
    }
    float mean = s / rows;
    float var  = s2 / rows - mean * mean;
    stats[c * 2]     = mean;
    stats[c * 2 + 1] = rsqrtf(var + BN_EPS);
}

// ---------------------------------------------------------------- bn apply + next-layer sqnorm
template<int C>
__global__ __launch_bounds__(256) void bn_apply_sq_kernel(
        float* __restrict__ h, const float* __restrict__ stats,
        const float* __restrict__ g, const float* __restrict__ be,
        float* __restrict__ sq, int total) {
    constexpr int VPL = C / 64;
    int gw = (int)((blockIdx.x * (size_t)blockDim.x + threadIdx.x) >> 6);
    int ln = threadIdx.x & 63;
    if (gw >= total) return;
    float ssum = 0.f;
#pragma unroll
    for (int u = 0; u < VPL; ++u) {
        int c = u * 64 + ln;
        float v = h[(size_t)gw * C + c];
        v = (v - stats[c * 2]) * stats[c * 2 + 1] * g[c] + be[c];
        h[(size_t)gw * C + c] = v;
        ssum += v * v;
    }
#pragma unroll
    for (int off = 32; off > 0; off >>= 1) ssum += __shfl_down(ssum, off, 64);
    if (ln == 0) sq[gw] = ssum;
}

// ---------------------------------------------------------------- final
__global__ void final_kernel(const float* __restrict__ g3, const float* __restrict__ b3,
                             const float* __restrict__ Wc, const float* __restrict__ bc,
                             float* __restrict__ out, int total) {
    int t = blockIdx.x * blockDim.x + threadIdx.x;
    if (t >= total * 16) return;
    int o = t & 15;
    int i = t >> 4;
    float acc = bc[o];
#pragma unroll
    for (int c = 0; c < 6; ++c) {
        float hm = 0.f;
#pragma unroll
        for (int h = 0; h < 8; ++h) hm += g3[(size_t)i * 48 + h * 6 + c];
        hm = hm * 0.125f + b3[c];
        acc += hm * Wc[c * 16 + o];
    }
    out[t] = acc;
}

static inline int cdiv(int a, int b) { return (a + b - 1) / b; }

extern "C" void kernel_launch(void* const* d_in, const int* in_sizes, int n_in,
                              void* d_out, int out_size, void* d_ws, size_t ws_size,
                              hipStream_t stream) {
    const float* x    = (const float*)d_in[0];
    const float* W1   = (const float*)d_in[2];
    const float* att1 = (const float*)d_in[3];
    const float* b1   = (const float*)d_in[4];
    const float* p1   = (const float*)d_in[5];
    const float* g1   = (const float*)d_in[6];
    const float* be1  = (const float*)d_in[7];
    const float* W2   = (const float*)d_in[8];
    const float* att2 = (const float*)d_in[9];
    const float* b2   = (const float*)d_in[10];
    const float* p2   = (const float*)d_in[11];
    const float* g2   = (const float*)d_in[12];
    const float* be2  = (const float*)d_in[13];
    const float* W3   = (const float*)d_in[14];
    const float* att3 = (const float*)d_in[15];
    const float* b3   = (const float*)d_in[16];
    const float* Wc   = (const float*)d_in[17];
    const float* bc   = (const float*)d_in[18];

    const int B = 8, N = 2048, T = B * N;
    const int NBLK = 256;
    (void)n_in; (void)in_sizes; (void)out_size;

    float* ws    = (float*)d_ws;
    float* bufA  = ws;                            // T*64
    float* bufB  = bufA + (size_t)T * 64;         // T*128
    float* bufC  = bufB + (size_t)T * 128;        // T*48
    float* sd    = bufC + (size_t)T * 48;         // T*8
    float* ss    = sd   + (size_t)T * 8;          // T*8
    float* sq    = ss   + (size_t)T * 8;          // T
    float* stats = sq   + T;                      // 256
    float* part  = stats + 256;                   // NBLK*2*128
    int*   idx   = (int*)(part + (size_t)NBLK * 256); // T*33
    float* Dxw   = (float*)(idx + (size_t)T * KTOT);  // max(T*128, PB*N*N)
    float* xw    = Dxw;

    size_t fixed_words = (size_t)(Dxw - ws);
    size_t avail_words = (ws_size / 4 > fixed_words) ? (ws_size / 4 - fixed_words) : 0;
    int PB = (int)(avail_words / ((size_t)N * N));
    if (PB < 1) PB = 1;
    if (PB > B) PB = B;

    const int BS = 256;
    const int nb = N / 64;

    // ================= Layer 1 (F=3 -> H=4,C=16 -> 64) =================
    sqnorm_kernel<3><<<cdiv(T, BS), BS, 0, stream>>>(x, sq, T);
    for (int b0 = 0; b0 < B; b0 += PB) {
        int pb = (b0 + PB <= B) ? PB : (B - b0);
        dist_kernel<3><<<dim3(nb, (nb + 1) / 2, pb), 256, 0, stream>>>(
            x + (size_t)b0 * N * 3, sq + (size_t)b0 * N, Dxw, N);
        knn_select_kernel<2048><<<pb * N / 4, 256, 0, stream>>>(Dxw, idx, b0);
    }
    linear_kernel<3, 64><<<cdiv(T * 64, BS), BS, 0, stream>>>(x, W1, xw, T);
    scores_kernel<4, 16><<<cdiv(T * 4, BS), BS, 0, stream>>>(xw, att1, sd, ss, T);
    gat_kernel<4, 16><<<cdiv(T * 64, BS), BS, 0, stream>>>(xw, sd, ss, idx, b1, p1, 0.2f, bufA, T);
    bn_partial_kernel<64><<<NBLK, 256, 0, stream>>>(bufA, part, T, NBLK);
    bn_finalize_kernel<64><<<1, 64, 0, stream>>>(part, stats, NBLK, T);
    bn_apply_sq_kernel<64><<<cdiv(T, 4), 256, 0, stream>>>(bufA, stats, g1, be1, sq, T);

    // ================= Layer 2 (F=64 -> H=2,C=64 -> 128) =================
    for (int b0 = 0; b0 < B; b0 += PB) {
        int pb = (b0 + PB <= B) ? PB : (B - b0);
        dist_kernel<64><<<dim3(nb, (nb + 1) / 2, pb), 256, 0, stream>>>(
            bufA + (size_t)b0 * N * 64, sq + (size_t)b0 * N, Dxw, N);
        knn_select_kernel<2048><<<pb * N / 4, 256, 0, stream>>>(Dxw, idx, b0);
    }
    linear_kernel<64, 128><<<cdiv(T * 128, BS), BS, 0, stream>>>(bufA, W2, xw, T);
    scores_kernel<2, 64><<<cdiv(T * 2, BS), BS, 0, stream>>>(xw, att2, sd, ss, T);
    gat_kernel<2, 64><<<cdiv(T * 2 * 64, BS), BS, 0, stream>>>(xw, sd, ss, idx, b2, p2, 0.2f, bufB, T);
    bn_partial_kernel<128><<<NBLK, 256, 0, stream>>>(bufB, part, T, NBLK);
    bn_finalize_kernel<128><<<1, 128, 0, stream>>>(part, stats, NBLK, T);
    bn_apply_sq_kernel<128><<<cdiv(T, 4), 256, 0, stream>>>(bufB, stats, g2, be2, sq, T);

    // ================= Layer 3 (F=128 -> H=8,C=6 -> mean -> 6) =================
    for (int b0 = 0; b0 < B; b0 += PB) {
        int pb = (b0 + PB <= B) ? PB : (B - b0);
        dist_kernel<128><<<dim3(nb, (nb + 1) / 2, pb), 256, 0, stream>>>(
            bufB + (size_t)b0 * N * 128, sq + (size_t)b0 * N, Dxw, N);
        knn_select_kernel<2048><<<pb * N / 4, 256, 0, stream>>>(Dxw, idx, b0);
    }
    linear_kernel<128, 48><<<cdiv(T * 48, BS), BS, 0, stream>>>(bufB, W3, xw, T);
    scores_kernel<8, 6><<<cdiv(T * 8, BS), BS, 0, stream>>>(xw, att3, sd, ss, T);
    gat_kernel<8, 6><<<cdiv(T * 64, BS), BS, 0, stream>>>(xw, sd, ss, idx, nullptr, nullptr, 0.5f, bufC, T);

    // ================= Final =================
    final_kernel<<<cdiv(T * 16, BS), BS, 0, stream>>>(bufC, b3, Wc, bc, (float*)d_out, T);
}

// Round 20
// 608.072 us; speedup vs baseline: 1.0246x; 1.0111x over previous
//
#include <hip/hip_runtime.h>
#include <hip/hip_bf16.h>

#define K_NN 32
#define KTOT 33
#define BN_EPS 1e-5f

typedef unsigned int uint32;
typedef unsigned long long ulong64;

__device__ __forceinline__ uint32 key_of_bits(uint32 u) {
    return u ^ ((u & 0x80000000u) ? 0xFFFFFFFFu : 0x80000000u);
}

// ---------------------------------------------------------------- sq norms (layer 1 input only)
template<int F>
__global__ void sqnorm_kernel(const float* __restrict__ x, float* __restrict__ sq, int total) {
    int i = blockIdx.x * blockDim.x + threadIdx.x;
    if (i >= total) return;
    float s = 0.f;
#pragma unroll
    for (int f = 0; f < F; ++f) { float v = x[(size_t)i * F + f]; s += v * v; }
    sq[i] = s;
}

// ---------------------------------------------------------------- symmetric distance matrix
// R17 config VERBATIM (measured best: 96us, 59% occ): upper-triangular
// 64x64 tiles + register mirror stores, 4x4 patch, ds_read_b128 fragments,
// KD=32. R18 (KD=32 2-tile, 26KB LDS) and R19 (KD=16 2-tile) both landed
// at the same 96us with collapsed occupancy -> this formulation's floor.
template<int F>
__global__ __launch_bounds__(256) void dist_kernel(
        const float* __restrict__ X, const float* __restrict__ sq,
        float* __restrict__ D, int N) {
    constexpr int KD = (F < 32) ? F : 32;
    __shared__ float As[KD][68];
    __shared__ float Bs[KD][68];
    const int bz = blockIdx.z;
    const float* Xb  = X  + (size_t)bz * N * F;
    const float* sqb = sq + (size_t)bz * N;
    float* Db = D + (size_t)bz * N * N;

    const int nb = N / 64;
    int t = blockIdx.x;
    int bi = (int)(((2.f * nb + 1.f) -
                    sqrtf((2.f * nb + 1.f) * (2.f * nb + 1.f) - 8.f * (float)t)) * 0.5f);
    if (bi >= nb) bi = nb - 1;
    if (bi < 0) bi = 0;
    while (bi > 0 && t < bi * nb - bi * (bi - 1) / 2) --bi;
    while (t >= (bi + 1) * nb - ((bi + 1) * bi) / 2) ++bi;
    int bj = bi + (t - (bi * nb - bi * (bi - 1) / 2));

    const int r0 = bi * 64, c0 = bj * 64;
    const int tid = threadIdx.x;
    const int tx = tid & 15, ty = tid >> 4;
    float acc[4][4] = {};
    for (int f0 = 0; f0 < F; f0 += KD) {
        __syncthreads();
        if constexpr (KD % 4 == 0) {
            constexpr int QPR = KD / 4;              // float4 quads per row
            constexpr int ELS = 64 * QPR;            // quad-elements per side
#pragma unroll
            for (int u = 0; u < ELS / 256; ++u) {
                int e = tid + u * 256;
                int r = e / QPR, kq = (e % QPR) * 4;
                float4 va = *(const float4*)&Xb[(size_t)(r0 + r) * F + f0 + kq];
                float4 vb = *(const float4*)&Xb[(size_t)(c0 + r) * F + f0 + kq];
                As[kq][r] = va.x; As[kq + 1][r] = va.y; As[kq + 2][r] = va.z; As[kq + 3][r] = va.w;
                Bs[kq][r] = vb.x; Bs[kq + 1][r] = vb.y; Bs[kq + 2][r] = vb.z; Bs[kq + 3][r] = vb.w;
            }
        } else {
            for (int e = tid; e < 64 * KD; e += 256) {
                int r = e / KD, k = e - r * KD;
                As[k][r] = Xb[(size_t)(r0 + r) * F + f0 + k];
                Bs[k][r] = Xb[(size_t)(c0 + r) * F + f0 + k];
            }
        }
        __syncthreads();
#pragma unroll
        for (int k = 0; k < KD; ++k) {
            float4 a4 = *(const float4*)&As[k][ty * 4];
            float4 b4 = *(const float4*)&Bs[k][tx * 4];
            const float* a = (const float*)&a4;
            const float* b = (const float*)&b4;
#pragma unroll
            for (int i = 0; i < 4; ++i)
#pragma unroll
                for (int j = 0; j < 4; ++j)
                    acc[i][j] += a[i] * b[j];
        }
    }
    float sr[4], sc[4];
#pragma unroll
    for (int u = 0; u < 4; ++u) {
        sr[u] = sqb[r0 + ty * 4 + u];
        sc[u] = sqb[c0 + tx * 4 + u];
    }
    float d4[4][4];
#pragma unroll
    for (int i = 0; i < 4; ++i) {
        int gr = r0 + ty * 4 + i;
        float4 v;
        float* vp = (float*)&v;
#pragma unroll
        for (int j = 0; j < 4; ++j) {
            int gc = c0 + tx * 4 + j;
            float d = sr[i] + sc[j] - 2.f * acc[i][j];
            if (gr == gc) d = 1e30f;
            d4[i][j] = d;
            vp[j] = d;
        }
        *(float4*)&Db[(size_t)gr * N + c0 + tx * 4] = v;
    }
    if (bi != bj) {
#pragma unroll
        for (int j = 0; j < 4; ++j) {
            int gc = c0 + tx * 4 + j;
            float4 v = make_float4(d4[0][j], d4[1][j], d4[2][j], d4[3][j]);
            *(float4*)&Db[(size_t)gc * N + r0 + ty * 4] = v;
        }
    }
}

// ---------------------------------------------------------------- wave-synchronous radix top-32
// R17 core with vectorized staging + scan-based eq-collection:
//  * lane ownership remapped to j = 256*(c>>2) + 4*ln + (c&3) so staging is
//    8 coalesced uint4 loads (was 32 scalar dword loads). Pass-1 wave-min
//    and histogram passes are mapping-agnostic.
//  * eq-collection: lane-local count + wave-scan (same machinery as the
//    less-pass) replaces 32 serial ballots. Eq order is lane-major; order
//    only matters when bit-exact key ties overflow 'need' (measure-zero
//    here; when eqcount==need all eq are selected regardless of order).
template<int N>
__global__ __launch_bounds__(256) void knn_select_kernel(
        const float* __restrict__ D, int* __restrict__ idx_out, int b0) {
    constexpr int CH = N / 64;                 // keys per lane (32)
    constexpr int NQ = N / 256;                // uint4 loads per lane (8)
    constexpr int HW = 4 * 264;                // words per wave (4 reps, padded)
    __shared__ int hist[4][HW];
    int wv = threadIdx.x >> 6;
    int ln = threadIdx.x & 63;
    int rep = (ln >> 4) & 3;
    int row = blockIdx.x * 4 + wv;
    int b   = b0 + row / N;
    int i   = row & (N - 1);
    const uint4* drow4 = (const uint4*)(D + (size_t)row * N);
    int* hw = hist[wv];

    uint32 kreg[CH];
#pragma unroll
    for (int q = 0; q < NQ; ++q) {
        uint4 v = drow4[q * 64 + ln];
        kreg[4 * q]     = key_of_bits(v.x);
        kreg[4 * q + 1] = key_of_bits(v.y);
        kreg[4 * q + 2] = key_of_bits(v.z);
        kreg[4 * q + 3] = key_of_bits(v.w);
    }
    // element index of kreg[c]: j = 256*(c>>2) + 4*ln + (c&3)

    uint32 prefix = 0;
    int need = K_NN;

    // ---- pass 1 (bits 31:24): iterative wave-min + count, no LDS
    {
        int vprev = -1, cum = 0, chosen = 0, fex = 0;
        while (true) {
            int lm = 256;
#pragma unroll
            for (int c = 0; c < CH; ++c) {
                int bc = (int)(kreg[c] >> 24);
                lm = (bc > vprev && bc < lm) ? bc : lm;
            }
#pragma unroll
            for (int off = 32; off > 0; off >>= 1) {
                int o = __shfl_xor(lm, off, 64);
                lm = (o < lm) ? o : lm;
            }
            int lc = 0;
#pragma unroll
            for (int c = 0; c < CH; ++c) lc += ((int)(kreg[c] >> 24) == lm);
#pragma unroll
            for (int off = 32; off > 0; off >>= 1) lc += __shfl_xor(lc, off, 64);
            if (cum + lc >= need) { chosen = lm; fex = cum; break; }
            cum += lc; vprev = lm;
        }
        prefix = ((uint32)chosen) << 24;
        need -= fex;
    }

    // ---- passes 2-4: replicated padded histogram (R16 layout win)
#pragma unroll
    for (int shift = 16; shift >= 0; shift -= 8) {
#pragma unroll
        for (int u = 0; u < (HW + 63) / 64; ++u) {
            int w = u * 64 + ln;
            if (w < HW) hw[w] = 0;
        }
        uint32 himask = (uint32)(~((1ull << (shift + 8)) - 1ull));
#pragma unroll
        for (int c = 0; c < CH; ++c) {
            uint32 k = kreg[c];
            if (((k ^ prefix) & himask) == 0) {
                int bin = (int)((k >> shift) & 255u);
                atomicAdd(&hw[rep * 264 + bin + (bin >> 5)], 1);
            }
        }
        int hh[4];
#pragma unroll
        for (int u = 0; u < 4; ++u) {
            int bin = 4 * ln + u;
            int bb = bin + (bin >> 5);
            hh[u] = hw[bb] + hw[264 + bb] + hw[528 + bb] + hw[792 + bb];
        }
        int s0 = hh[0], s1 = s0 + hh[1], s2 = s1 + hh[2], s3 = s2 + hh[3];
        int run = s3;
#pragma unroll
        for (int off = 1; off < 64; off <<= 1) {
            int v = __shfl_up(run, off, 64);
            if (ln >= off) run += v;
        }
        int ex = run - s3;
        int fbin = -1, fex = 0;
        if      (ex      < need && ex + s0 >= need) { fbin = 4 * ln;     fex = ex; }
        else if (ex + s0 < need && ex + s1 >= need) { fbin = 4 * ln + 1; fex = ex + s0; }
        else if (ex + s1 < need && ex + s2 >= need) { fbin = 4 * ln + 2; fex = ex + s1; }
        else if (ex + s2 < need && ex + s3 >= need) { fbin = 4 * ln + 3; fex = ex + s2; }
        ulong64 bm = __ballot(fbin >= 0);
        int srcl = __ffsll((long long)bm) - 1;
        int bin  = __shfl(fbin, srcl, 64);
        int bex  = __shfl(fex,  srcl, 64);
        prefix |= ((uint32)bin) << shift;
        need -= bex;
    }
    // prefix = key of the 32nd smallest; cl = #strictly-less, need = eq-slots
    int cl = K_NN - need;
    int gbase = b * N;
    int* op = idx_out + (size_t)(gbase + i) * KTOT;

    // less-keys: lane-local collection (order-free)
    int lcnt = 0;
#pragma unroll
    for (int c = 0; c < CH; ++c) lcnt += (kreg[c] < prefix) ? 1 : 0;
    int scan = lcnt;
#pragma unroll
    for (int off = 1; off < 64; off <<= 1) {
        int v = __shfl_up(scan, off, 64);
        if (ln >= off) scan += v;
    }
    int wbase = scan - lcnt;
#pragma unroll
    for (int c = 0; c < CH; ++c) {
        if (kreg[c] < prefix) {
            int j = 256 * (c >> 2) + 4 * ln + (c & 3);
            op[wbase] = gbase + j; ++wbase;
        }
    }

    // eq-keys: lane-local count + wave-scan (lane-major order)
    int ecnt = 0;
#pragma unroll
    for (int c = 0; c < CH; ++c) ecnt += (kreg[c] == prefix) ? 1 : 0;
    int escan = ecnt;
#pragma unroll
    for (int off = 1; off < 64; off <<= 1) {
        int v = __shfl_up(escan, off, 64);
        if (ln >= off) escan += v;
    }
    int ebase = cl + (escan - ecnt);
#pragma unroll
    for (int c = 0; c < CH; ++c) {
        if (kreg[c] == prefix) {
            if (ebase < K_NN) {
                int j = 256 * (c >> 2) + 4 * ln + (c & 3);
                op[ebase] = gbase + j;
            }
            ++ebase;
        }
    }
    if (ln == 0) op[K_NN] = gbase + i;
}

// ---------------------------------------------------------------- linear
template<int IN, int OUT>
__global__ void linear_kernel(const float* __restrict__ x, const float* __restrict__ W,
                              float* __restrict__ y, int total) {
    int t = blockIdx.x * blockDim.x + threadIdx.x;
    if (t >= total * OUT) return;
    int o = t % OUT;
    int i = t / OUT;
    float a0 = 0.f, a1 = 0.f, a2 = 0.f, a3 = 0.f;
#pragma unroll
    for (int f = 0; f + 3 < IN; f += 4) {
        a0 += x[(size_t)i * IN + f]     * W[(f) * OUT + o];
        a1 += x[(size_t)i * IN + f + 1] * W[(f + 1) * OUT + o];
        a2 += x[(size_t)i * IN + f + 2] * W[(f + 2) * OUT + o];
        a3 += x[(size_t)i * IN + f + 3] * W[(f + 3) * OUT + o];
    }
#pragma unroll
    for (int f = IN & ~3; f < IN; ++f) a0 += x[(size_t)i * IN + f] * W[f * OUT + o];
    y[t] = (a0 + a1) + (a2 + a3);
}

// ---------------------------------------------------------------- scores
template<int H, int C>
__global__ void scores_kernel(const float* __restrict__ xw, const float* __restrict__ att,
                              float* __restrict__ sd, float* __restrict__ ss, int total) {
    int t = blockIdx.x * blockDim.x + threadIdx.x;
    if (t >= total * H) return;
    int h = t % H;
    int i = t / H;
    float d = 0.f, s = 0.f;
#pragma unroll
    for (int c = 0; c < C; ++c) {
        float v = xw[(size_t)i * H * C + h * C + c];
        d += v * att[h * 2 * C + c];
        s += v * att[h * 2 * C + C + c];
    }
    sd[t] = d;
    ss[t] = s;
}

// ---------------------------------------------------------------- gat gather
template<int H, int C>
__global__ __launch_bounds__(256) void gat_kernel(
        const float* __restrict__ xw, const float* __restrict__ sd,
        const float* __restrict__ ss, const int* __restrict__ idx,
        const float* __restrict__ bias, const float* __restrict__ prelu,
        float slope, float* __restrict__ out, int total) {
    constexpr int HC = H * C;
    constexpr int WPN = (HC + 63) / 64;
    int gw = (int)((blockIdx.x * (size_t)blockDim.x + threadIdx.x) >> 6);
    int ln = threadIdx.x & 63;
    int i  = gw / WPN;
    int wsub = gw - i * WPN;
    if (i >= total) return;
    int ch = wsub * 64 + ln;
    bool act = ch < HC;
    int h = act ? (ch / C) : 0;
    const int* ip = idx + (size_t)i * KTOT;
    int jl = (ln < KTOT) ? ip[ln] : 0;
    float sdi = act ? sd[(size_t)i * H + h] : 0.f;
    float m = -1e30f, l = 0.f, acc = 0.f;
    for (int k = 0; k < KTOT; ++k) {
        int j = __shfl(jl, k, 64);
        float e = sdi + (act ? ss[(size_t)j * H + h] : 0.f);
        e = (e >= 0.f) ? e : slope * e;
        float mn = fmaxf(m, e);
        float scl = __expf(m - mn);
        float w   = __expf(e - mn);
        l = l * scl + w;
        float xv = act ? xw[(size_t)j * HC + ch] : 0.f;
        acc = acc * scl + w * xv;
        m = mn;
    }
    if (act) {
        float r = acc / l;
        if (bias) r += bias[ch];
        if (prelu) { float p0 = prelu[0]; r = (r >= 0.f) ? r : p0 * r; }
        out[(size_t)i * HC + ch] = r;
    }
}

// ---------------------------------------------------------------- bn partial sums (coalesced)
template<int C>
__global__ __launch_bounds__(256) void bn_partial_kernel(
        const float* __restrict__ h, float* __restrict__ part, int rows, int nblk) {
    constexpr int RPT = 256 / C;
    int c  = threadIdx.x & (C - 1);
    int rs = threadIdx.x / C;
    int rpb = (rows + nblk - 1) / nblk;
    int r0 = blockIdx.x * rpb;
    int r1 = r0 + rpb; if (r1 > rows) r1 = rows;
    float s = 0.f, s2 = 0.f;
    for (int r = r0 + rs; r < r1; r += RPT) {
        float v = h[(size_t)r * C + c];
        s += v; s2 += v * v;
    }
    __shared__ float ls[2][256];
    ls[0][threadIdx.x] = s; ls[1][threadIdx.x] = s2;
    __syncthreads();
    if (rs == 0) {
#pragma unroll
        for (int g = 1; g < RPT; ++g) { s += ls[0][g * C + c]; s2 += ls[1][g * C + c]; }
        part[(size_t)blockIdx.x * 2 * C + c]     = s;
        part[(size_t)blockIdx.x * 2 * C + C + c] = s2;
    }
}

template<int C>
__global__ void bn_finalize_kernel(const float* __restrict__ part, float* __restrict__ stats,
                                   int nblk, int rows) {
    int c = threadIdx.x;
    float s = 0.f, s2 = 0.f;
    for (int p = 0; p < nblk; ++p) {
        s  += part[(size_t)p * 2 * C + c];
        s2 += part[(size_t)p * 2 * C + C + c];
    }
    float mean = s / rows;
    float var  = s2 / rows - mean * mean;
    stats[c * 2]     = mean;
    stats[c * 2 + 1] = rsqrtf(var + BN_EPS);
}

// ---------------------------------------------------------------- bn apply + next-layer sqnorm
template<int C>
__global__ __launch_bounds__(256) void bn_apply_sq_kernel(
        float* __restrict__ h, const float* __restrict__ stats,
        const float* __restrict__ g, const float* __restrict__ be,
        float* __restrict__ sq, int total) {
    constexpr int VPL = C / 64;
    int gw = (int)((blockIdx.x * (size_t)blockDim.x + threadIdx.x) >> 6);
    int ln = threadIdx.x & 63;
    if (gw >= total) return;
    float ssum = 0.f;
#pragma unroll
    for (int u = 0; u < VPL; ++u) {
        int c = u * 64 + ln;
        float v = h[(size_t)gw * C + c];
        v = (v - stats[c * 2]) * stats[c * 2 + 1] * g[c] + be[c];
        h[(size_t)gw * C + c] = v;
        ssum += v * v;
    }
#pragma unroll
    for (int off = 32; off > 0; off >>= 1) ssum += __shfl_down(ssum, off, 64);
    if (ln == 0) sq[gw] = ssum;
}

// ---------------------------------------------------------------- final
__global__ void final_kernel(const float* __restrict__ g3, const float* __restrict__ b3,
                             const float* __restrict__ Wc, const float* __restrict__ bc,
                             float* __restrict__ out, int total) {
    int t = blockIdx.x * blockDim.x + threadIdx.x;
    if (t >= total * 16) return;
    int o = t & 15;
    int i = t >> 4;
    float acc = bc[o];
#pragma unroll
    for (int c = 0; c < 6; ++c) {
        float hm = 0.f;
#pragma unroll
        for (int h = 0; h < 8; ++h) hm += g3[(size_t)i * 48 + h * 6 + c];
        hm = hm * 0.125f + b3[c];
        acc += hm * Wc[c * 16 + o];
    }
    out[t] = acc;
}

static inline int cdiv(int a, int b) { return (a + b - 1) / b; }

extern "C" void kernel_launch(void* const* d_in, const int* in_sizes, int n_in,
                              void* d_out, int out_size, void* d_ws, size_t ws_size,
                              hipStream_t stream) {
    const float* x    = (const float*)d_in[0];
    const float* W1   = (const float*)d_in[2];
    const float* att1 = (const float*)d_in[3];
    const float* b1   = (const float*)d_in[4];
    const float* p1   = (const float*)d_in[5];
    const float* g1   = (const float*)d_in[6];
    const float* be1  = (const float*)d_in[7];
    const float* W2   = (const float*)d_in[8];
    const float* att2 = (const float*)d_in[9];
    const float* b2   = (const float*)d_in[10];
    const float* p2   = (const float*)d_in[11];
    const float* g2   = (const float*)d_in[12];
    const float* be2  = (const float*)d_in[13];
    const float* W3   = (const float*)d_in[14];
    const float* att3 = (const float*)d_in[15];
    const float* b3   = (const float*)d_in[16];
    const float* Wc   = (const float*)d_in[17];
    const float* bc   = (const float*)d_in[18];

    const int B = 8, N = 2048, T = B * N;
    const int NBLK = 256;
    (void)n_in; (void)in_sizes; (void)out_size;

    float* ws    = (float*)d_ws;
    float* bufA  = ws;                            // T*64
    float* bufB  = bufA + (size_t)T * 64;         // T*128
    float* bufC  = bufB + (size_t)T * 128;        // T*48
    float* sd    = bufC + (size_t)T * 48;         // T*8
    float* ss    = sd   + (size_t)T * 8;          // T*8
    float* sq    = ss   + (size_t)T * 8;          // T
    float* stats = sq   + T;                      // 256
    float* part  = stats + 256;                   // NBLK*2*128
    int*   idx   = (int*)(part + (size_t)NBLK * 256); // T*33
    float* Dxw   = (float*)(idx + (size_t)T * KTOT);  // max(T*128, PB*N*N)
    float* xw    = Dxw;

    size_t fixed_words = (size_t)(Dxw - ws);
    size_t avail_words = (ws_size / 4 > fixed_words) ? (ws_size / 4 - fixed_words) : 0;
    int PB = (int)(avail_words / ((size_t)N * N));
    if (PB < 1) PB = 1;
    if (PB > B) PB = B;

    const int BS = 256;
    const int nb = N / 64;
    const int NTRI = nb * (nb + 1) / 2;

    // ================= Layer 1 (F=3 -> H=4,C=16 -> 64) =================
    sqnorm_kernel<3><<<cdiv(T, BS), BS, 0, stream>>>(x, sq, T);
    for (int b0 = 0; b0 < B; b0 += PB) {
        int pb = (b0 + PB <= B) ? PB : (B - b0);
        dist_kernel<3><<<dim3(NTRI, 1, pb), 256, 0, stream>>>(
            x + (size_t)b0 * N * 3, sq + (size_t)b0 * N, Dxw, N);
        knn_select_kernel<2048><<<pb * N / 4, 256, 0, stream>>>(Dxw, idx, b0);
    }
    linear_kernel<3, 64><<<cdiv(T * 64, BS), BS, 0, stream>>>(x, W1, xw, T);
    scores_kernel<4, 16><<<cdiv(T * 4, BS), BS, 0, stream>>>(xw, att1, sd, ss, T);
    gat_kernel<4, 16><<<cdiv(T * 64, BS), BS, 0, stream>>>(xw, sd, ss, idx, b1, p1, 0.2f, bufA, T);
    bn_partial_kernel<64><<<NBLK, 256, 0, stream>>>(bufA, part, T, NBLK);
    bn_finalize_kernel<64><<<1, 64, 0, stream>>>(part, stats, NBLK, T);
    bn_apply_sq_kernel<64><<<cdiv(T, 4), 256, 0, stream>>>(bufA, stats, g1, be1, sq, T);

    // ================= Layer 2 (F=64 -> H=2,C=64 -> 128) =================
    for (int b0 = 0; b0 < B; b0 += PB) {
        int pb = (b0 + PB <= B) ? PB : (B - b0);
        dist_kernel<64><<<dim3(NTRI, 1, pb), 256, 0, stream>>>(
            bufA + (size_t)b0 * N * 64, sq + (size_t)b0 * N, Dxw, N);
        knn_select_kernel<2048><<<pb * N / 4, 256, 0, stream>>>(Dxw, idx, b0);
    }
    linear_kernel<64, 128><<<cdiv(T * 128, BS), BS, 0, stream>>>(bufA, W2, xw, T);
    scores_kernel<2, 64><<<cdiv(T * 2, BS), BS, 0, stream>>>(xw, att2, sd, ss, T);
    gat_kernel<2, 64><<<cdiv(T * 2 * 64, BS), BS, 0, stream>>>(xw, sd, ss, idx, b2, p2, 0.2f, bufB, T);
    bn_partial_kernel<128><<<NBLK, 256, 0, stream>>>(bufB, part, T, NBLK);
    bn_finalize_kernel<128><<<1, 128, 0, stream>>>(part, stats, NBLK, T);
    bn_apply_sq_kernel<128><<<cdiv(T, 4), 256, 0, stream>>>(bufB, stats, g2, be2, sq, T);

    // ================= Layer 3 (F=128 -> H=8,C=6 -> mean -> 6) =================
    for (int b0 = 0; b0 < B; b0 += PB) {
        int pb = (b0 + PB <= B) ? PB : (B - b0);
        dist_kernel<128><<<dim3(NTRI, 1, pb), 256, 0, stream>>>(
            bufB + (size_t)b0 * N * 128, sq + (size_t)b0 * N, Dxw, N);
        knn_select_kernel<2048><<<pb * N / 4, 256, 0, stream>>>(Dxw, idx, b0);
    }
    linear_kernel<128, 48><<<cdiv(T * 48, BS), BS, 0, stream>>>(bufB, W3, xw, T);
    scores_kernel<8, 6><<<cdiv(T * 8, BS), BS, 0, stream>>>(xw, att3, sd, ss, T);
    gat_kernel<8, 6><<<cdiv(T * 64, BS), BS, 0, stream>>>(xw, sd, ss, idx, nullptr, nullptr, 0.5f, bufC, T);

    // ================= Final =================
    final_kernel<<<cdiv(T * 16, BS), BS, 0, stream>>>(bufC, b3, Wc, bc, (float*)d_out, T);
}

// Round 21
// 552.605 us; speedup vs baseline: 1.1274x; 1.1004x over previous
//
#include <hip/hip_runtime.h>
#include <hip/hip_bf16.h>

#define K_NN 32
#define KTOT 33
#define BN_EPS 1e-5f

typedef unsigned int uint32;
typedef unsigned long long ulong64;
typedef __attribute__((ext_vector_type(8))) short bf16x8;
typedef __attribute__((ext_vector_type(4))) float f32x4;

__device__ __forceinline__ uint32 key_of_bits(uint32 u) {
    return u ^ ((u & 0x80000000u) ? 0xFFFFFFFFu : 0x80000000u);
}

__device__ __forceinline__ uint32 bf_round(uint32 u) {
    return (u + 0x7FFFu + ((u >> 16) & 1u)) >> 16;   // RNE to bf16 bits
}

// ---------------------------------------------------------------- sq norms (layer 1 input only)
template<int F>
__global__ void sqnorm_kernel(const float* __restrict__ x, float* __restrict__ sq, int total) {
    int i = blockIdx.x * blockDim.x + threadIdx.x;
    if (i >= total) return;
    float s = 0.f;
#pragma unroll
    for (int f = 0; f < F; ++f) { float v = x[(size_t)i * F + f]; s += v * v; }
    sq[i] = s;
}

// ---------------------------------------------------------------- VALU distance (layer 1, F=3)
template<int F>
__global__ __launch_bounds__(256) void dist_kernel(
        const float* __restrict__ X, const float* __restrict__ sq,
        float* __restrict__ D, int N) {
    constexpr int KD = (F < 32) ? F : 32;
    __shared__ float As[KD][68];
    __shared__ float Bs[KD][68];
    const int bz = blockIdx.z;
    const float* Xb  = X  + (size_t)bz * N * F;
    const float* sqb = sq + (size_t)bz * N;
    float* Db = D + (size_t)bz * N * N;

    const int nb = N / 64;
    int t = blockIdx.x;
    int bi = (int)(((2.f * nb + 1.f) -
                    sqrtf((2.f * nb + 1.f) * (2.f * nb + 1.f) - 8.f * (float)t)) * 0.5f);
    if (bi >= nb) bi = nb - 1;
    if (bi < 0) bi = 0;
    while (bi > 0 && t < bi * nb - bi * (bi - 1) / 2) --bi;
    while (t >= (bi + 1) * nb - ((bi + 1) * bi) / 2) ++bi;
    int bj = bi + (t - (bi * nb - bi * (bi - 1) / 2));

    const int r0 = bi * 64, c0 = bj * 64;
    const int tid = threadIdx.x;
    const int tx = tid & 15, ty = tid >> 4;
    float acc[4][4] = {};
    for (int f0 = 0; f0 < F; f0 += KD) {
        __syncthreads();
        for (int e = tid; e < 64 * KD; e += 256) {
            int r = e / KD, k = e - r * KD;
            As[k][r] = Xb[(size_t)(r0 + r) * F + f0 + k];
            Bs[k][r] = Xb[(size_t)(c0 + r) * F + f0 + k];
        }
        __syncthreads();
#pragma unroll
        for (int k = 0; k < KD; ++k) {
            float4 a4 = *(const float4*)&As[k][ty * 4];
            float4 b4 = *(const float4*)&Bs[k][tx * 4];
            const float* a = (const float*)&a4;
            const float* b = (const float*)&b4;
#pragma unroll
            for (int i = 0; i < 4; ++i)
#pragma unroll
                for (int j = 0; j < 4; ++j)
                    acc[i][j] += a[i] * b[j];
        }
    }
    float sr[4], sc[4];
#pragma unroll
    for (int u = 0; u < 4; ++u) {
        sr[u] = sqb[r0 + ty * 4 + u];
        sc[u] = sqb[c0 + tx * 4 + u];
    }
    float d4[4][4];
#pragma unroll
    for (int i = 0; i < 4; ++i) {
        int gr = r0 + ty * 4 + i;
        float4 v;
        float* vp = (float*)&v;
#pragma unroll
        for (int j = 0; j < 4; ++j) {
            int gc = c0 + tx * 4 + j;
            float d = sr[i] + sc[j] - 2.f * acc[i][j];
            if (gr == gc) d = 1e30f;
            d4[i][j] = d;
            vp[j] = d;
        }
        *(float4*)&Db[(size_t)gr * N + c0 + tx * 4] = v;
    }
    if (bi != bj) {
#pragma unroll
        for (int j = 0; j < 4; ++j) {
            int gc = c0 + tx * 4 + j;
            float4 v = make_float4(d4[0][j], d4[1][j], d4[2][j], d4[3][j]);
            *(float4*)&Db[(size_t)gc * N + r0 + ty * 4] = v;
        }
    }
}

// ---------------------------------------------------------------- MFMA distance (F=64/128)
// Gram via bf16 3-way split (h1+h2+h3, err ~2^-24 -> fp32-equivalent):
// 6 mfma_f32_16x16x32_bf16 products per 16x16 subtile per K=32 chunk
// (h1h1, h1h2, h2h1, h1h3, h3h1, h2h2). 4 waves/block, each computes a
// 32x32 quadrant as 2x2 subtiles. Split done on the fly during staging.
// C/D mapping (m89): col=lane&15, row=(lane>>4)*4+reg. A/B fragment:
// row/col=lane&15, k=8*(lane>>4)+j. Gram symmetry makes A/B-role
// ambiguity harmless. Triangular grid + mirror stores as before.
template<int F>
__global__ __launch_bounds__(256) void dist_mfma_kernel(
        const float* __restrict__ X, const float* __restrict__ sq,
        float* __restrict__ D, int N) {
    __shared__ short Ab[3][64][32];
    __shared__ short Bb[3][64][32];
    const int bz = blockIdx.z;
    const float* Xb  = X  + (size_t)bz * N * F;
    const float* sqb = sq + (size_t)bz * N;
    float* Db = D + (size_t)bz * N * N;

    const int nb = N / 64;
    int t = blockIdx.x;
    int bi = (int)(((2.f * nb + 1.f) -
                    sqrtf((2.f * nb + 1.f) * (2.f * nb + 1.f) - 8.f * (float)t)) * 0.5f);
    if (bi >= nb) bi = nb - 1;
    if (bi < 0) bi = 0;
    while (bi > 0 && t < bi * nb - bi * (bi - 1) / 2) --bi;
    while (t >= (bi + 1) * nb - ((bi + 1) * bi) / 2) ++bi;
    int bj = bi + (t - (bi * nb - bi * (bi - 1) / 2));

    const int r0 = bi * 64, c0 = bj * 64;
    const int tid = threadIdx.x;
    const int ln  = tid & 63;
    const int wv  = tid >> 6;
    const int wr  = (wv >> 1) * 32;      // wave row offset in 64x64 tile
    const int wc  = (wv & 1) * 32;       // wave col offset
    const int frow = ln & 15;            // fragment point index
    const int kb   = (ln >> 4) * 8;      // fragment k base

    f32x4 acc[2][2];
#pragma unroll
    for (int si = 0; si < 2; ++si)
#pragma unroll
        for (int sj = 0; sj < 2; ++sj)
            acc[si][sj] = (f32x4){0.f, 0.f, 0.f, 0.f};

    const int pt = tid >> 2;             // staging: point 0..63
    const int kq = (tid & 3) * 8;        // staging: k base 0/8/16/24

    for (int f0 = 0; f0 < F; f0 += 32) {
        __syncthreads();
        {
            const float* ra = &Xb[(size_t)(r0 + pt) * F + f0 + kq];
            const float* rb = &Xb[(size_t)(c0 + pt) * F + f0 + kq];
            float4 a0 = *(const float4*)ra, a1 = *(const float4*)(ra + 4);
            float4 b0 = *(const float4*)rb, b1 = *(const float4*)(rb + 4);
            float av[8] = {a0.x, a0.y, a0.z, a0.w, a1.x, a1.y, a1.z, a1.w};
            float bv[8] = {b0.x, b0.y, b0.z, b0.w, b1.x, b1.y, b1.z, b1.w};
            bf16x8 a_1, a_2, a_3, b_1, b_2, b_3;
#pragma unroll
            for (int j = 0; j < 8; ++j) {
                float x = av[j];
                uint32 r1 = bf_round(__float_as_uint(x));
                float f1 = __uint_as_float(r1 << 16);
                float d1 = x - f1;
                uint32 r2 = bf_round(__float_as_uint(d1));
                float f2 = __uint_as_float(r2 << 16);
                uint32 r3 = bf_round(__float_as_uint(d1 - f2));
                a_1[j] = (short)r1; a_2[j] = (short)r2; a_3[j] = (short)r3;
                x = bv[j];
                r1 = bf_round(__float_as_uint(x));
                f1 = __uint_as_float(r1 << 16);
                d1 = x - f1;
                r2 = bf_round(__float_as_uint(d1));
                f2 = __uint_as_float(r2 << 16);
                r3 = bf_round(__float_as_uint(d1 - f2));
                b_1[j] = (short)r1; b_2[j] = (short)r2; b_3[j] = (short)r3;
            }
            *(bf16x8*)&Ab[0][pt][kq] = a_1;
            *(bf16x8*)&Ab[1][pt][kq] = a_2;
            *(bf16x8*)&Ab[2][pt][kq] = a_3;
            *(bf16x8*)&Bb[0][pt][kq] = b_1;
            *(bf16x8*)&Bb[1][pt][kq] = b_2;
            *(bf16x8*)&Bb[2][pt][kq] = b_3;
        }
        __syncthreads();
        bf16x8 af[3][2], bfr[3][2];
#pragma unroll
        for (int lev = 0; lev < 3; ++lev)
#pragma unroll
            for (int s = 0; s < 2; ++s) {
                af[lev][s]  = *(const bf16x8*)&Ab[lev][wr + s * 16 + frow][kb];
                bfr[lev][s] = *(const bf16x8*)&Bb[lev][wc + s * 16 + frow][kb];
            }
#pragma unroll
        for (int si = 0; si < 2; ++si)
#pragma unroll
            for (int sj = 0; sj < 2; ++sj) {
                f32x4 a = acc[si][sj];
                a = __builtin_amdgcn_mfma_f32_16x16x32_bf16(af[0][si], bfr[0][sj], a, 0, 0, 0);
                a = __builtin_amdgcn_mfma_f32_16x16x32_bf16(af[0][si], bfr[1][sj], a, 0, 0, 0);
                a = __builtin_amdgcn_mfma_f32_16x16x32_bf16(af[1][si], bfr[0][sj], a, 0, 0, 0);
                a = __builtin_amdgcn_mfma_f32_16x16x32_bf16(af[0][si], bfr[2][sj], a, 0, 0, 0);
                a = __builtin_amdgcn_mfma_f32_16x16x32_bf16(af[2][si], bfr[0][sj], a, 0, 0, 0);
                a = __builtin_amdgcn_mfma_f32_16x16x32_bf16(af[1][si], bfr[1][sj], a, 0, 0, 0);
                acc[si][sj] = a;
            }
    }

    // epilogue: d = sq_r + sq_c - 2*acc; diag -> 1e30; store transposed
    // (per-lane float4, covers diag tiles fully) + straight (quarter-
    // coalesced scalar) for off-diag mirror.
#pragma unroll
    for (int si = 0; si < 2; ++si) {
        int gr0 = r0 + wr + si * 16 + (ln >> 4) * 4;
#pragma unroll
        for (int sj = 0; sj < 2; ++sj) {
            int gc = c0 + wc + sj * 16 + (ln & 15);
            float sqc = sqb[gc];
            float4 v;
            float* vp = (float*)&v;
#pragma unroll
            for (int q = 0; q < 4; ++q) {
                int gr = gr0 + q;
                float d = sqb[gr] + sqc - 2.f * acc[si][sj][q];
                if (gr == gc) d = 1e30f;
                vp[q] = d;
                if (bi != bj) Db[(size_t)gr * N + gc] = d;
            }
            *(float4*)&Db[(size_t)gc * N + gr0] = v;
        }
    }
}

// ---------------------------------------------------------------- wave-synchronous radix top-32
// R20 core: vectorized uint4 staging (j = 256*(c>>2)+4*ln+(c&3)); pass 1 =
// iterative wave-min; passes 2-4 = 4-replica rep-major padded histogram;
// lane-local scan collection for less- and eq-keys.
template<int N>
__global__ __launch_bounds__(256) void knn_select_kernel(
        const float* __restrict__ D, int* __restrict__ idx_out, int b0) {
    constexpr int CH = N / 64;
    constexpr int NQ = N / 256;
    constexpr int HW = 4 * 264;
    __shared__ int hist[4][HW];
    int wv = threadIdx.x >> 6;
    int ln = threadIdx.x & 63;
    int rep = (ln >> 4) & 3;
    int row = blockIdx.x * 4 + wv;
    int b   = b0 + row / N;
    int i   = row & (N - 1);
    const uint4* drow4 = (const uint4*)(D + (size_t)row * N);
    int* hw = hist[wv];

    uint32 kreg[CH];
#pragma unroll
    for (int q = 0; q < NQ; ++q) {
        uint4 v = drow4[q * 64 + ln];
        kreg[4 * q]     = key_of_bits(v.x);
        kreg[4 * q + 1] = key_of_bits(v.y);
        kreg[4 * q + 2] = key_of_bits(v.z);
        kreg[4 * q + 3] = key_of_bits(v.w);
    }

    uint32 prefix = 0;
    int need = K_NN;

    {
        int vprev = -1, cum = 0, chosen = 0, fex = 0;
        while (true) {
            int lm = 256;
#pragma unroll
            for (int c = 0; c < CH; ++c) {
                int bc = (int)(kreg[c] >> 24);
                lm = (bc > vprev && bc < lm) ? bc : lm;
            }
#pragma unroll
            for (int off = 32; off > 0; off >>= 1) {
                int o = __shfl_xor(lm, off, 64);
                lm = (o < lm) ? o : lm;
            }
            int lc = 0;
#pragma unroll
            for (int c = 0; c < CH; ++c) lc += ((int)(kreg[c] >> 24) == lm);
#pragma unroll
            for (int off = 32; off > 0; off >>= 1) lc += __shfl_xor(lc, off, 64);
            if (cum + lc >= need) { chosen = lm; fex = cum; break; }
            cum += lc; vprev = lm;
        }
        prefix = ((uint32)chosen) << 24;
        need -= fex;
    }

#pragma unroll
    for (int shift = 16; shift >= 0; shift -= 8) {
#pragma unroll
        for (int u = 0; u < (HW + 63) / 64; ++u) {
            int w = u * 64 + ln;
            if (w < HW) hw[w] = 0;
        }
        uint32 himask = (uint32)(~((1ull << (shift + 8)) - 1ull));
#pragma unroll
        for (int c = 0; c < CH; ++c) {
            uint32 k = kreg[c];
            if (((k ^ prefix) & himask) == 0) {
                int bin = (int)((k >> shift) & 255u);
                atomicAdd(&hw[rep * 264 + bin + (bin >> 5)], 1);
            }
        }
        int hh[4];
#pragma unroll
        for (int u = 0; u < 4; ++u) {
            int bin = 4 * ln + u;
            int bb = bin + (bin >> 5);
            hh[u] = hw[bb] + hw[264 + bb] + hw[528 + bb] + hw[792 + bb];
        }
        int s0 = hh[0], s1 = s0 + hh[1], s2 = s1 + hh[2], s3 = s2 + hh[3];
        int run = s3;
#pragma unroll
        for (int off = 1; off < 64; off <<= 1) {
            int v = __shfl_up(run, off, 64);
            if (ln >= off) run += v;
        }
        int ex = run - s3;
        int fbin = -1, fex = 0;
        if      (ex      < need && ex + s0 >= need) { fbin = 4 * ln;     fex = ex; }
        else if (ex + s0 < need && ex + s1 >= need) { fbin = 4 * ln + 1; fex = ex + s0; }
        else if (ex + s1 < need && ex + s2 >= need) { fbin = 4 * ln + 2; fex = ex + s1; }
        else if (ex + s2 < need && ex + s3 >= need) { fbin = 4 * ln + 3; fex = ex + s2; }
        ulong64 bm = __ballot(fbin >= 0);
        int srcl = __ffsll((long long)bm) - 1;
        int bin  = __shfl(fbin, srcl, 64);
        int bex  = __shfl(fex,  srcl, 64);
        prefix |= ((uint32)bin) << shift;
        need -= bex;
    }
    int cl = K_NN - need;
    int gbase = b * N;
    int* op = idx_out + (size_t)(gbase + i) * KTOT;

    int lcnt = 0;
#pragma unroll
    for (int c = 0; c < CH; ++c) lcnt += (kreg[c] < prefix) ? 1 : 0;
    int scan = lcnt;
#pragma unroll
    for (int off = 1; off < 64; off <<= 1) {
        int v = __shfl_up(scan, off, 64);
        if (ln >= off) scan += v;
    }
    int wbase = scan - lcnt;
#pragma unroll
    for (int c = 0; c < CH; ++c) {
        if (kreg[c] < prefix) {
            int j = 256 * (c >> 2) + 4 * ln + (c & 3);
            op[wbase] = gbase + j; ++wbase;
        }
    }

    int ecnt = 0;
#pragma unroll
    for (int c = 0; c < CH; ++c) ecnt += (kreg[c] == prefix) ? 1 : 0;
    int escan = ecnt;
#pragma unroll
    for (int off = 1; off < 64; off <<= 1) {
        int v = __shfl_up(escan, off, 64);
        if (ln >= off) escan += v;
    }
    int ebase = cl + (escan - ecnt);
#pragma unroll
    for (int c = 0; c < CH; ++c) {
        if (kreg[c] == prefix) {
            if (ebase < K_NN) {
                int j = 256 * (c >> 2) + 4 * ln + (c & 3);
                op[ebase] = gbase + j;
            }
            ++ebase;
        }
    }
    if (ln == 0) op[K_NN] = gbase + i;
}

// ---------------------------------------------------------------- linear
template<int IN, int OUT>
__global__ void linear_kernel(const float* __restrict__ x, const float* __restrict__ W,
                              float* __restrict__ y, int total) {
    int t = blockIdx.x * blockDim.x + threadIdx.x;
    if (t >= total * OUT) return;
    int o = t % OUT;
    int i = t / OUT;
    float a0 = 0.f, a1 = 0.f, a2 = 0.f, a3 = 0.f;
#pragma unroll
    for (int f = 0; f + 3 < IN; f += 4) {
        a0 += x[(size_t)i * IN + f]     * W[(f) * OUT + o];
        a1 += x[(size_t)i * IN + f + 1] * W[(f + 1) * OUT + o];
        a2 += x[(size_t)i * IN + f + 2] * W[(f + 2) * OUT + o];
        a3 += x[(size_t)i * IN + f + 3] * W[(f + 3) * OUT + o];
    }
#pragma unroll
    for (int f = IN & ~3; f < IN; ++f) a0 += x[(size_t)i * IN + f] * W[f * OUT + o];
    y[t] = (a0 + a1) + (a2 + a3);
}

// ---------------------------------------------------------------- scores
template<int H, int C>
__global__ void scores_kernel(const float* __restrict__ xw, const float* __restrict__ att,
                              float* __restrict__ sd, float* __restrict__ ss, int total) {
    int t = blockIdx.x * blockDim.x + threadIdx.x;
    if (t >= total * H) return;
    int h = t % H;
    int i = t / H;
    float d = 0.f, s = 0.f;
#pragma unroll
    for (int c = 0; c < C; ++c) {
        float v = xw[(size_t)i * H * C + h * C + c];
        d += v * att[h * 2 * C + c];
        s += v * att[h * 2 * C + C + c];
    }
    sd[t] = d;
    ss[t] = s;
}

// ---------------------------------------------------------------- gat gather
template<int H, int C>
__global__ __launch_bounds__(256) void gat_kernel(
        const float* __restrict__ xw, const float* __restrict__ sd,
        const float* __restrict__ ss, const int* __restrict__ idx,
        const float* __restrict__ bias, const float* __restrict__ prelu,
        float slope, float* __restrict__ out, int total) {
    constexpr int HC = H * C;
    constexpr int WPN = (HC + 63) / 64;
    int gw = (int)((blockIdx.x * (size_t)blockDim.x + threadIdx.x) >> 6);
    int ln = threadIdx.x & 63;
    int i  = gw / WPN;
    int wsub = gw - i * WPN;
    if (i >= total) return;
    int ch = wsub * 64 + ln;
    bool act = ch < HC;
    int h = act ? (ch / C) : 0;
    const int* ip = idx + (size_t)i * KTOT;
    int jl = (ln < KTOT) ? ip[ln] : 0;
    float sdi = act ? sd[(size_t)i * H + h] : 0.f;
    float m = -1e30f, l = 0.f, acc = 0.f;
    for (int k = 0; k < KTOT; ++k) {
        int j = __shfl(jl, k, 64);
        float e = sdi + (act ? ss[(size_t)j * H + h] : 0.f);
        e = (e >= 0.f) ? e : slope * e;
        float mn = fmaxf(m, e);
        float scl = __expf(m - mn);
        float w   = __expf(e - mn);
        l = l * scl + w;
        float xv = act ? xw[(size_t)j * HC + ch] : 0.f;
        acc = acc * scl + w * xv;
        m = mn;
    }
    if (act) {
        float r = acc / l;
        if (bias) r += bias[ch];
        if (prelu) { float p0 = prelu[0]; r = (r >= 0.f) ? r : p0 * r; }
        out[(size_t)i * HC + ch] = r;
    }
}

// ---------------------------------------------------------------- bn partial sums (coalesced)
template<int C>
__global__ __launch_bounds__(256) void bn_partial_kernel(
        const float* __restrict__ h, float* __restrict__ part, int rows, int nblk) {
    constexpr int RPT = 256 / C;
    int c  = threadIdx.x & (C - 1);
    int rs = threadIdx.x / C;
    int rpb = (rows + nblk - 1) / nblk;
    int r0 = blockIdx.x * rpb;
    int r1 = r0 + rpb; if (r1 > rows) r1 = rows;
    float s = 0.f, s2 = 0.f;
    for (int r = r0 + rs; r < r1; r += RPT) {
        float v = h[(size_t)r * C + c];
        s += v; s2 += v * v;
    }
    __shared__ float ls[2][256];
    ls[0][threadIdx.x] = s; ls[1][threadIdx.x] = s2;
    __syncthreads();
    if (rs == 0) {
#pragma unroll
        for (int g = 1; g < RPT; ++g) { s += ls[0][g * C + c]; s2 += ls[1][g * C + c]; }
        part[(size_t)blockIdx.x * 2 * C + c]     = s;
        part[(size_t)blockIdx.x * 2 * C + C + c] = s2;
    }
}

template<int C>
__global__ void bn_finalize_kernel(const float* __restrict__ part, float* __restrict__ stats,
                                   int nblk, int rows) {
    int c = threadIdx.x;
    float s = 0.f, s2 = 0.f;
    for (int p = 0; p < nblk; ++p) {
        s  += part[(size_t)p * 2 * C + c];
        s2 += part[(size_t)p * 2 * C + C + c];
    }
    float mean = s / rows;
    float var  = s2 / rows - mean * mean;
    stats[c * 2]     = mean;
    stats[c * 2 + 1] = rsqrtf(var + BN_EPS);
}

// ---------------------------------------------------------------- bn apply + next-layer sqnorm
template<int C>
__global__ __launch_bounds__(256) void bn_apply_sq_kernel(
        float* __restrict__ h, const float* __restrict__ stats,
        const float* __restrict__ g, const float* __restrict__ be,
        float* __restrict__ sq, int total) {
    constexpr int VPL = C / 64;
    int gw = (int)((blockIdx.x * (size_t)blockDim.x + threadIdx.x) >> 6);
    int ln = threadIdx.x & 63;
    if (gw >= total) return;
    float ssum = 0.f;
#pragma unroll
    for (int u = 0; u < VPL; ++u) {
        int c = u * 64 + ln;
        float v = h[(size_t)gw * C + c];
        v = (v - stats[c * 2]) * stats[c * 2 + 1] * g[c] + be[c];
        h[(size_t)gw * C + c] = v;
        ssum += v * v;
    }
#pragma unroll
    for (int off = 32; off > 0; off >>= 1) ssum += __shfl_down(ssum, off, 64);
    if (ln == 0) sq[gw] = ssum;
}

// ---------------------------------------------------------------- final
__global__ void final_kernel(const float* __restrict__ g3, const float* __restrict__ b3,
                             const float* __restrict__ Wc, const float* __restrict__ bc,
                             float* __restrict__ out, int total) {
    int t = blockIdx.x * blockDim.x + threadIdx.x;
    if (t >= total * 16) return;
    int o = t & 15;
    int i = t >> 4;
    float acc = bc[o];
#pragma unroll
    for (int c = 0; c < 6; ++c) {
        float hm = 0.f;
#pragma unroll
        for (int h = 0; h < 8; ++h) hm += g3[(size_t)i * 48 + h * 6 + c];
        hm = hm * 0.125f + b3[c];
        acc += hm * Wc[c * 16 + o];
    }
    out[t] = acc;
}

static inline int cdiv(int a, int b) { return (a + b - 1) / b; }

extern "C" void kernel_launch(void* const* d_in, const int* in_sizes, int n_in,
                              void* d_out, int out_size, void* d_ws, size_t ws_size,
                              hipStream_t stream) {
    const float* x    = (const float*)d_in[0];
    const float* W1   = (const float*)d_in[2];
    const float* att1 = (const float*)d_in[3];
    const float* b1   = (const float*)d_in[4];
    const float* p1   = (const float*)d_in[5];
    const float* g1   = (const float*)d_in[6];
    const float* be1  = (const float*)d_in[7];
    const float* W2   = (const float*)d_in[8];
    const float* att2 = (const float*)d_in[9];
    const float* b2   = (const float*)d_in[10];
    const float* p2   = (const float*)d_in[11];
    const float* g2   = (const float*)d_in[12];
    const float* be2  = (const float*)d_in[13];
    const float* W3   = (const float*)d_in[14];
    const float* att3 = (const float*)d_in[15];
    const float* b3   = (const float*)d_in[16];
    const float* Wc   = (const float*)d_in[17];
    const float* bc   = (const float*)d_in[18];

    const int B = 8, N = 2048, T = B * N;
    const int NBLK = 256;
    (void)n_in; (void)in_sizes; (void)out_size;

    float* ws    = (float*)d_ws;
    float* bufA  = ws;                            // T*64
    float* bufB  = bufA + (size_t)T * 64;         // T*128
    float* bufC  = bufB + (size_t)T * 128;        // T*48
    float* sd    = bufC + (size_t)T * 48;         // T*8
    float* ss    = sd   + (size_t)T * 8;          // T*8
    float* sq    = ss   + (size_t)T * 8;          // T
    float* stats = sq   + T;                      // 256
    float* part  = stats + 256;                   // NBLK*2*128
    int*   idx   = (int*)(part + (size_t)NBLK * 256); // T*33
    float* Dxw   = (float*)(idx + (size_t)T * KTOT);  // max(T*128, PB*N*N)
    float* xw    = Dxw;

    size_t fixed_words = (size_t)(Dxw - ws);
    size_t avail_words = (ws_size / 4 > fixed_words) ? (ws_size / 4 - fixed_words) : 0;
    int PB = (int)(avail_words / ((size_t)N * N));
    if (PB < 1) PB = 1;
    if (PB > B) PB = B;

    const int BS = 256;
    const int nb = N / 64;
    const int NTRI = nb * (nb + 1) / 2;

    // ================= Layer 1 (F=3 -> H=4,C=16 -> 64) =================
    sqnorm_kernel<3><<<cdiv(T, BS), BS, 0, stream>>>(x, sq, T);
    for (int b0 = 0; b0 < B; b0 += PB) {
        int pb = (b0 + PB <= B) ? PB : (B - b0);
        dist_kernel<3><<<dim3(NTRI, 1, pb), 256, 0, stream>>>(
            x + (size_t)b0 * N * 3, sq + (size_t)b0 * N, Dxw, N);
        knn_select_kernel<2048><<<pb * N / 4, 256, 0, stream>>>(Dxw, idx, b0);
    }
    linear_kernel<3, 64><<<cdiv(T * 64, BS), BS, 0, stream>>>(x, W1, xw, T);
    scores_kernel<4, 16><<<cdiv(T * 4, BS), BS, 0, stream>>>(xw, att1, sd, ss, T);
    gat_kernel<4, 16><<<cdiv(T * 64, BS), BS, 0, stream>>>(xw, sd, ss, idx, b1, p1, 0.2f, bufA, T);
    bn_partial_kernel<64><<<NBLK, 256, 0, stream>>>(bufA, part, T, NBLK);
    bn_finalize_kernel<64><<<1, 64, 0, stream>>>(part, stats, NBLK, T);
    bn_apply_sq_kernel<64><<<cdiv(T, 4), 256, 0, stream>>>(bufA, stats, g1, be1, sq, T);

    // ================= Layer 2 (F=64 -> H=2,C=64 -> 128) =================
    for (int b0 = 0; b0 < B; b0 += PB) {
        int pb = (b0 + PB <= B) ? PB : (B - b0);
        dist_mfma_kernel<64><<<dim3(NTRI, 1, pb), 256, 0, stream>>>(
            bufA + (size_t)b0 * N * 64, sq + (size_t)b0 * N, Dxw, N);
        knn_select_kernel<2048><<<pb * N / 4, 256, 0, stream>>>(Dxw, idx, b0);
    }
    linear_kernel<64, 128><<<cdiv(T * 128, BS), BS, 0, stream>>>(bufA, W2, xw, T);
    scores_kernel<2, 64><<<cdiv(T * 2, BS), BS, 0, stream>>>(xw, att2, sd, ss, T);
    gat_kernel<2, 64><<<cdiv(T * 2 * 64, BS), BS, 0, stream>>>(xw, sd, ss, idx, b2, p2, 0.2f, bufB, T);
    bn_partial_kernel<128><<<NBLK, 256, 0, stream>>>(bufB, part, T, NBLK);
    bn_finalize_kernel<128><<<1, 128, 0, stream>>>(part, stats, NBLK, T);
    bn_apply_sq_kernel<128><<<cdiv(T, 4), 256, 0, stream>>>(bufB, stats, g2, be2, sq, T);

    // ================= Layer 3 (F=128 -> H=8,C=6 -> mean -> 6) =================
    for (int b0 = 0; b0 < B; b0 += PB) {
        int pb = (b0 + PB <= B) ? PB : (B - b0);
        dist_mfma_kernel<128><<<dim3(NTRI, 1, pb), 256, 0, stream>>>(
            bufB + (size_t)b0 * N * 128, sq + (size_t)b0 * N, Dxw, N);
        knn_select_kernel<2048><<<pb * N / 4, 256, 0, stream>>>(Dxw, idx, b0);
    }
    linear_kernel<128, 48><<<cdiv(T * 48, BS), BS, 0, stream>>>(bufB, W3, xw, T);
    scores_kernel<8, 6><<<cdiv(T * 8, BS), BS, 0, stream>>>(xw, att3, sd, ss, T);
    gat_kernel<8, 6><<<cdiv(T * 64, BS), BS, 0, stream>>>(xw, sd, ss, idx, nullptr, nullptr, 0.5f, bufC, T);

    // ================= Final =================
    final_kernel<<<cdiv(T * 16, BS), BS, 0, stream>>>(bufC, b3, Wc, bc, (float*)d_out, T);
}

// Round 22
// 436.161 us; speedup vs baseline: 1.4284x; 1.2670x over previous
//
#include <hip/hip_runtime.h>
#include <hip/hip_bf16.h>

#define K_NN 32
#define KTOT 33
#define BN_EPS 1e-5f

typedef unsigned int uint32;
typedef unsigned long long ulong64;
typedef __attribute__((ext_vector_type(8))) short bf16x8;
typedef __attribute__((ext_vector_type(4))) float f32x4;

__device__ __forceinline__ uint32 key_of_bits(uint32 u) {
    return u ^ ((u & 0x80000000u) ? 0xFFFFFFFFu : 0x80000000u);
}

__device__ __forceinline__ uint32 bf_round(uint32 u) {
    return (u + 0x7FFFu + ((u >> 16) & 1u)) >> 16;   // RNE to bf16 bits
}

// ---------------------------------------------------------------- sq norms (layer 1 input only)
template<int F>
__global__ void sqnorm_kernel(const float* __restrict__ x, float* __restrict__ sq, int total) {
    int i = blockIdx.x * blockDim.x + threadIdx.x;
    if (i >= total) return;
    float s = 0.f;
#pragma unroll
    for (int f = 0; f < F; ++f) { float v = x[(size_t)i * F + f]; s += v * v; }
    sq[i] = s;
}

// ---------------------------------------------------------------- VALU distance (layer 1, F=3)
template<int F>
__global__ __launch_bounds__(256) void dist_kernel(
        const float* __restrict__ X, const float* __restrict__ sq,
        float* __restrict__ D, int N) {
    constexpr int KD = (F < 32) ? F : 32;
    __shared__ float As[KD][68];
    __shared__ float Bs[KD][68];
    const int bz = blockIdx.z;
    const float* Xb  = X  + (size_t)bz * N * F;
    const float* sqb = sq + (size_t)bz * N;
    float* Db = D + (size_t)bz * N * N;

    const int nb = N / 64;
    int t = blockIdx.x;
    int bi = (int)(((2.f * nb + 1.f) -
                    sqrtf((2.f * nb + 1.f) * (2.f * nb + 1.f) - 8.f * (float)t)) * 0.5f);
    if (bi >= nb) bi = nb - 1;
    if (bi < 0) bi = 0;
    while (bi > 0 && t < bi * nb - bi * (bi - 1) / 2) --bi;
    while (t >= (bi + 1) * nb - ((bi + 1) * bi) / 2) ++bi;
    int bj = bi + (t - (bi * nb - bi * (bi - 1) / 2));

    const int r0 = bi * 64, c0 = bj * 64;
    const int tid = threadIdx.x;
    const int tx = tid & 15, ty = tid >> 4;
    float acc[4][4] = {};
    for (int f0 = 0; f0 < F; f0 += KD) {
        __syncthreads();
        for (int e = tid; e < 64 * KD; e += 256) {
            int r = e / KD, k = e - r * KD;
            As[k][r] = Xb[(size_t)(r0 + r) * F + f0 + k];
            Bs[k][r] = Xb[(size_t)(c0 + r) * F + f0 + k];
        }
        __syncthreads();
#pragma unroll
        for (int k = 0; k < KD; ++k) {
            float4 a4 = *(const float4*)&As[k][ty * 4];
            float4 b4 = *(const float4*)&Bs[k][tx * 4];
            const float* a = (const float*)&a4;
            const float* b = (const float*)&b4;
#pragma unroll
            for (int i = 0; i < 4; ++i)
#pragma unroll
                for (int j = 0; j < 4; ++j)
                    acc[i][j] += a[i] * b[j];
        }
    }
    float sr[4], sc[4];
#pragma unroll
    for (int u = 0; u < 4; ++u) {
        sr[u] = sqb[r0 + ty * 4 + u];
        sc[u] = sqb[c0 + tx * 4 + u];
    }
    float d4[4][4];
#pragma unroll
    for (int i = 0; i < 4; ++i) {
        int gr = r0 + ty * 4 + i;
        float4 v;
        float* vp = (float*)&v;
#pragma unroll
        for (int j = 0; j < 4; ++j) {
            int gc = c0 + tx * 4 + j;
            float d = sr[i] + sc[j] - 2.f * acc[i][j];
            if (gr == gc) d = 1e30f;
            d4[i][j] = d;
            vp[j] = d;
        }
        *(float4*)&Db[(size_t)gr * N + c0 + tx * 4] = v;
    }
    if (bi != bj) {
#pragma unroll
        for (int j = 0; j < 4; ++j) {
            int gc = c0 + tx * 4 + j;
            float4 v = make_float4(d4[0][j], d4[1][j], d4[2][j], d4[3][j]);
            *(float4*)&Db[(size_t)gc * N + r0 + ty * 4] = v;
        }
    }
}

// ---------------------------------------------------------------- MFMA distance (F=64/128)
// Gram via bf16 3-way split (h1+h2+h3, err ~2^-24 -> fp32-equivalent):
// 6 mfma_f32_16x16x32_bf16 products per 16x16 subtile per K=32 chunk.
// 4 waves/block, each a 32x32 quadrant as 2x2 subtiles. R21 verified
// (absmax unchanged vs VALU fp32 path).
template<int F>
__global__ __launch_bounds__(256) void dist_mfma_kernel(
        const float* __restrict__ X, const float* __restrict__ sq,
        float* __restrict__ D, int N) {
    __shared__ short Ab[3][64][32];
    __shared__ short Bb[3][64][32];
    const int bz = blockIdx.z;
    const float* Xb  = X  + (size_t)bz * N * F;
    const float* sqb = sq + (size_t)bz * N;
    float* Db = D + (size_t)bz * N * N;

    const int nb = N / 64;
    int t = blockIdx.x;
    int bi = (int)(((2.f * nb + 1.f) -
                    sqrtf((2.f * nb + 1.f) * (2.f * nb + 1.f) - 8.f * (float)t)) * 0.5f);
    if (bi >= nb) bi = nb - 1;
    if (bi < 0) bi = 0;
    while (bi > 0 && t < bi * nb - bi * (bi - 1) / 2) --bi;
    while (t >= (bi + 1) * nb - ((bi + 1) * bi) / 2) ++bi;
    int bj = bi + (t - (bi * nb - bi * (bi - 1) / 2));

    const int r0 = bi * 64, c0 = bj * 64;
    const int tid = threadIdx.x;
    const int ln  = tid & 63;
    const int wv  = tid >> 6;
    const int wr  = (wv >> 1) * 32;
    const int wc  = (wv & 1) * 32;
    const int frow = ln & 15;
    const int kb   = (ln >> 4) * 8;

    f32x4 acc[2][2];
#pragma unroll
    for (int si = 0; si < 2; ++si)
#pragma unroll
        for (int sj = 0; sj < 2; ++sj)
            acc[si][sj] = (f32x4){0.f, 0.f, 0.f, 0.f};

    const int pt = tid >> 2;
    const int kq = (tid & 3) * 8;

    for (int f0 = 0; f0 < F; f0 += 32) {
        __syncthreads();
        {
            const float* ra = &Xb[(size_t)(r0 + pt) * F + f0 + kq];
            const float* rb = &Xb[(size_t)(c0 + pt) * F + f0 + kq];
            float4 a0 = *(const float4*)ra, a1 = *(const float4*)(ra + 4);
            float4 b0 = *(const float4*)rb, b1 = *(const float4*)(rb + 4);
            float av[8] = {a0.x, a0.y, a0.z, a0.w, a1.x, a1.y, a1.z, a1.w};
            float bv[8] = {b0.x, b0.y, b0.z, b0.w, b1.x, b1.y, b1.z, b1.w};
            bf16x8 a_1, a_2, a_3, b_1, b_2, b_3;
#pragma unroll
            for (int j = 0; j < 8; ++j) {
                float x = av[j];
                uint32 r1 = bf_round(__float_as_uint(x));
                float f1 = __uint_as_float(r1 << 16);
                float d1 = x - f1;
                uint32 r2 = bf_round(__float_as_uint(d1));
                float f2 = __uint_as_float(r2 << 16);
                uint32 r3 = bf_round(__float_as_uint(d1 - f2));
                a_1[j] = (short)r1; a_2[j] = (short)r2; a_3[j] = (short)r3;
                x = bv[j];
                r1 = bf_round(__float_as_uint(x));
                f1 = __uint_as_float(r1 << 16);
                d1 = x - f1;
                r2 = bf_round(__float_as_uint(d1));
                f2 = __uint_as_float(r2 << 16);
                r3 = bf_round(__float_as_uint(d1 - f2));
                b_1[j] = (short)r1; b_2[j] = (short)r2; b_3[j] = (short)r3;
            }
            *(bf16x8*)&Ab[0][pt][kq] = a_1;
            *(bf16x8*)&Ab[1][pt][kq] = a_2;
            *(bf16x8*)&Ab[2][pt][kq] = a_3;
            *(bf16x8*)&Bb[0][pt][kq] = b_1;
            *(bf16x8*)&Bb[1][pt][kq] = b_2;
            *(bf16x8*)&Bb[2][pt][kq] = b_3;
        }
        __syncthreads();
        bf16x8 af[3][2], bfr[3][2];
#pragma unroll
        for (int lev = 0; lev < 3; ++lev)
#pragma unroll
            for (int s = 0; s < 2; ++s) {
                af[lev][s]  = *(const bf16x8*)&Ab[lev][wr + s * 16 + frow][kb];
                bfr[lev][s] = *(const bf16x8*)&Bb[lev][wc + s * 16 + frow][kb];
            }
#pragma unroll
        for (int si = 0; si < 2; ++si)
#pragma unroll
            for (int sj = 0; sj < 2; ++sj) {
                f32x4 a = acc[si][sj];
                a = __builtin_amdgcn_mfma_f32_16x16x32_bf16(af[0][si], bfr[0][sj], a, 0, 0, 0);
                a = __builtin_amdgcn_mfma_f32_16x16x32_bf16(af[0][si], bfr[1][sj], a, 0, 0, 0);
                a = __builtin_amdgcn_mfma_f32_16x16x32_bf16(af[1][si], bfr[0][sj], a, 0, 0, 0);
                a = __builtin_amdgcn_mfma_f32_16x16x32_bf16(af[0][si], bfr[2][sj], a, 0, 0, 0);
                a = __builtin_amdgcn_mfma_f32_16x16x32_bf16(af[2][si], bfr[0][sj], a, 0, 0, 0);
                a = __builtin_amdgcn_mfma_f32_16x16x32_bf16(af[1][si], bfr[1][sj], a, 0, 0, 0);
                acc[si][sj] = a;
            }
    }

#pragma unroll
    for (int si = 0; si < 2; ++si) {
        int gr0 = r0 + wr + si * 16 + (ln >> 4) * 4;
#pragma unroll
        for (int sj = 0; sj < 2; ++sj) {
            int gc = c0 + wc + sj * 16 + (ln & 15);
            float sqc = sqb[gc];
            float4 v;
            float* vp = (float*)&v;
#pragma unroll
            for (int q = 0; q < 4; ++q) {
                int gr = gr0 + q;
                float d = sqb[gr] + sqc - 2.f * acc[si][sj][q];
                if (gr == gc) d = 1e30f;
                vp[q] = d;
                if (bi != bj) Db[(size_t)gr * N + gc] = d;
            }
            *(float4*)&Db[(size_t)gc * N + gr0] = v;
        }
    }
}

// ---------------------------------------------------------------- wave-synchronous radix top-32
template<int N>
__global__ __launch_bounds__(256) void knn_select_kernel(
        const float* __restrict__ D, int* __restrict__ idx_out, int b0) {
    constexpr int CH = N / 64;
    constexpr int NQ = N / 256;
    constexpr int HW = 4 * 264;
    __shared__ int hist[4][HW];
    int wv = threadIdx.x >> 6;
    int ln = threadIdx.x & 63;
    int rep = (ln >> 4) & 3;
    int row = blockIdx.x * 4 + wv;
    int b   = b0 + row / N;
    int i   = row & (N - 1);
    const uint4* drow4 = (const uint4*)(D + (size_t)row * N);
    int* hw = hist[wv];

    uint32 kreg[CH];
#pragma unroll
    for (int q = 0; q < NQ; ++q) {
        uint4 v = drow4[q * 64 + ln];
        kreg[4 * q]     = key_of_bits(v.x);
        kreg[4 * q + 1] = key_of_bits(v.y);
        kreg[4 * q + 2] = key_of_bits(v.z);
        kreg[4 * q + 3] = key_of_bits(v.w);
    }

    uint32 prefix = 0;
    int need = K_NN;

    {
        int vprev = -1, cum = 0, chosen = 0, fex = 0;
        while (true) {
            int lm = 256;
#pragma unroll
            for (int c = 0; c < CH; ++c) {
                int bc = (int)(kreg[c] >> 24);
                lm = (bc > vprev && bc < lm) ? bc : lm;
            }
#pragma unroll
            for (int off = 32; off > 0; off >>= 1) {
                int o = __shfl_xor(lm, off, 64);
                lm = (o < lm) ? o : lm;
            }
            int lc = 0;
#pragma unroll
            for (int c = 0; c < CH; ++c) lc += ((int)(kreg[c] >> 24) == lm);
#pragma unroll
            for (int off = 32; off > 0; off >>= 1) lc += __shfl_xor(lc, off, 64);
            if (cum + lc >= need) { chosen = lm; fex = cum; break; }
            cum += lc; vprev = lm;
        }
        prefix = ((uint32)chosen) << 24;
        need -= fex;
    }

#pragma unroll
    for (int shift = 16; shift >= 0; shift -= 8) {
#pragma unroll
        for (int u = 0; u < (HW + 63) / 64; ++u) {
            int w = u * 64 + ln;
            if (w < HW) hw[w] = 0;
        }
        uint32 himask = (uint32)(~((1ull << (shift + 8)) - 1ull));
#pragma unroll
        for (int c = 0; c < CH; ++c) {
            uint32 k = kreg[c];
            if (((k ^ prefix) & himask) == 0) {
                int bin = (int)((k >> shift) & 255u);
                atomicAdd(&hw[rep * 264 + bin + (bin >> 5)], 1);
            }
        }
        int hh[4];
#pragma unroll
        for (int u = 0; u < 4; ++u) {
            int bin = 4 * ln + u;
            int bb = bin + (bin >> 5);
            hh[u] = hw[bb] + hw[264 + bb] + hw[528 + bb] + hw[792 + bb];
        }
        int s0 = hh[0], s1 = s0 + hh[1], s2 = s1 + hh[2], s3 = s2 + hh[3];
        int run = s3;
#pragma unroll
        for (int off = 1; off < 64; off <<= 1) {
            int v = __shfl_up(run, off, 64);
            if (ln >= off) run += v;
        }
        int ex = run - s3;
        int fbin = -1, fex = 0;
        if      (ex      < need && ex + s0 >= need) { fbin = 4 * ln;     fex = ex; }
        else if (ex + s0 < need && ex + s1 >= need) { fbin = 4 * ln + 1; fex = ex + s0; }
        else if (ex + s1 < need && ex + s2 >= need) { fbin = 4 * ln + 2; fex = ex + s1; }
        else if (ex + s2 < need && ex + s3 >= need) { fbin = 4 * ln + 3; fex = ex + s2; }
        ulong64 bm = __ballot(fbin >= 0);
        int srcl = __ffsll((long long)bm) - 1;
        int bin  = __shfl(fbin, srcl, 64);
        int bex  = __shfl(fex,  srcl, 64);
        prefix |= ((uint32)bin) << shift;
        need -= bex;
    }
    int cl = K_NN - need;
    int gbase = b * N;
    int* op = idx_out + (size_t)(gbase + i) * KTOT;

    int lcnt = 0;
#pragma unroll
    for (int c = 0; c < CH; ++c) lcnt += (kreg[c] < prefix) ? 1 : 0;
    int scan = lcnt;
#pragma unroll
    for (int off = 1; off < 64; off <<= 1) {
        int v = __shfl_up(scan, off, 64);
        if (ln >= off) scan += v;
    }
    int wbase = scan - lcnt;
#pragma unroll
    for (int c = 0; c < CH; ++c) {
        if (kreg[c] < prefix) {
            int j = 256 * (c >> 2) + 4 * ln + (c & 3);
            op[wbase] = gbase + j; ++wbase;
        }
    }

    int ecnt = 0;
#pragma unroll
    for (int c = 0; c < CH; ++c) ecnt += (kreg[c] == prefix) ? 1 : 0;
    int escan = ecnt;
#pragma unroll
    for (int off = 1; off < 64; off <<= 1) {
        int v = __shfl_up(escan, off, 64);
        if (ln >= off) escan += v;
    }
    int ebase = cl + (escan - ecnt);
#pragma unroll
    for (int c = 0; c < CH; ++c) {
        if (kreg[c] == prefix) {
            if (ebase < K_NN) {
                int j = 256 * (c >> 2) + 4 * ln + (c & 3);
                op[ebase] = gbase + j;
            }
            ++ebase;
        }
    }
    if (ln == 0) op[K_NN] = gbase + i;
}

// ---------------------------------------------------------------- linear
template<int IN, int OUT>
__global__ void linear_kernel(const float* __restrict__ x, const float* __restrict__ W,
                              float* __restrict__ y, int total) {
    int t = blockIdx.x * blockDim.x + threadIdx.x;
    if (t >= total * OUT) return;
    int o = t % OUT;
    int i = t / OUT;
    float a0 = 0.f, a1 = 0.f, a2 = 0.f, a3 = 0.f;
#pragma unroll
    for (int f = 0; f + 3 < IN; f += 4) {
        a0 += x[(size_t)i * IN + f]     * W[(f) * OUT + o];
        a1 += x[(size_t)i * IN + f + 1] * W[(f + 1) * OUT + o];
        a2 += x[(size_t)i * IN + f + 2] * W[(f + 2) * OUT + o];
        a3 += x[(size_t)i * IN + f + 3] * W[(f + 3) * OUT + o];
    }
#pragma unroll
    for (int f = IN & ~3; f < IN; ++f) a0 += x[(size_t)i * IN + f] * W[f * OUT + o];
    y[t] = (a0 + a1) + (a2 + a3);
}

// ---------------------------------------------------------------- scores
template<int H, int C>
__global__ void scores_kernel(const float* __restrict__ xw, const float* __restrict__ att,
                              float* __restrict__ sd, float* __restrict__ ss, int total) {
    int t = blockIdx.x * blockDim.x + threadIdx.x;
    if (t >= total * H) return;
    int h = t % H;
    int i = t / H;
    float d = 0.f, s = 0.f;
#pragma unroll
    for (int c = 0; c < C; ++c) {
        float v = xw[(size_t)i * H * C + h * C + c];
        d += v * att[h * 2 * C + c];
        s += v * att[h * 2 * C + C + c];
    }
    sd[t] = d;
    ss[t] = s;
}

// ---------------------------------------------------------------- gat gather
template<int H, int C>
__global__ __launch_bounds__(256) void gat_kernel(
        const float* __restrict__ xw, const float* __restrict__ sd,
        const float* __restrict__ ss, const int* __restrict__ idx,
        const float* __restrict__ bias, const float* __restrict__ prelu,
        float slope, float* __restrict__ out, int total) {
    constexpr int HC = H * C;
    constexpr int WPN = (HC + 63) / 64;
    int gw = (int)((blockIdx.x * (size_t)blockDim.x + threadIdx.x) >> 6);
    int ln = threadIdx.x & 63;
    int i  = gw / WPN;
    int wsub = gw - i * WPN;
    if (i >= total) return;
    int ch = wsub * 64 + ln;
    bool act = ch < HC;
    int h = act ? (ch / C) : 0;
    const int* ip = idx + (size_t)i * KTOT;
    int jl = (ln < KTOT) ? ip[ln] : 0;
    float sdi = act ? sd[(size_t)i * H + h] : 0.f;
    float m = -1e30f, l = 0.f, acc = 0.f;
    for (int k = 0; k < KTOT; ++k) {
        int j = __shfl(jl, k, 64);
        float e = sdi + (act ? ss[(size_t)j * H + h] : 0.f);
        e = (e >= 0.f) ? e : slope * e;
        float mn = fmaxf(m, e);
        float scl = __expf(m - mn);
        float w   = __expf(e - mn);
        l = l * scl + w;
        float xv = act ? xw[(size_t)j * HC + ch] : 0.f;
        acc = acc * scl + w * xv;
        m = mn;
    }
    if (act) {
        float r = acc / l;
        if (bias) r += bias[ch];
        if (prelu) { float p0 = prelu[0]; r = (r >= 0.f) ? r : p0 * r; }
        out[(size_t)i * HC + ch] = r;
    }
}

// ---------------------------------------------------------------- bn partial sums (coalesced)
template<int C>
__global__ __launch_bounds__(256) void bn_partial_kernel(
        const float* __restrict__ h, float* __restrict__ part, int rows, int nblk) {
    constexpr int RPT = 256 / C;
    int c  = threadIdx.x & (C - 1);
    int rs = threadIdx.x / C;
    int rpb = (rows + nblk - 1) / nblk;
    int r0 = blockIdx.x * rpb;
    int r1 = r0 + rpb; if (r1 > rows) r1 = rows;
    float s = 0.f, s2 = 0.f;
    for (int r = r0 + rs; r < r1; r += RPT) {
        float v = h[(size_t)r * C + c];
        s += v; s2 += v * v;
    }
    __shared__ float ls[2][256];
    ls[0][threadIdx.x] = s; ls[1][threadIdx.x] = s2;
    __syncthreads();
    if (rs == 0) {
#pragma unroll
        for (int g = 1; g < RPT; ++g) { s += ls[0][g * C + c]; s2 += ls[1][g * C + c]; }
        part[(size_t)blockIdx.x * 2 * C + c]     = s;
        part[(size_t)blockIdx.x * 2 * C + C + c] = s2;
    }
}

// ---------------------------------------------------------------- bn finalize (parallel)
// R21 finding: the serial one-block version cost 63us (256 dependent global
// loads, VALUBusy ~0). Grid = C blocks x 256 threads: thread p loads
// part[p][c] in parallel, wave shfl + cross-wave LDS reduce -> ~3us.
template<int C>
__global__ __launch_bounds__(256) void bn_finalize_kernel(
        const float* __restrict__ part, float* __restrict__ stats,
        int nblk, int rows) {
    int c = blockIdx.x;
    int p = threadIdx.x;                 // nblk == 256
    float s  = part[(size_t)p * 2 * C + c];
    float s2 = part[(size_t)p * 2 * C + C + c];
#pragma unroll
    for (int off = 32; off > 0; off >>= 1) {
        s  += __shfl_down(s, off, 64);
        s2 += __shfl_down(s2, off, 64);
    }
    __shared__ float red[2][4];
    int wv = p >> 6, ln = p & 63;
    if (ln == 0) { red[0][wv] = s; red[1][wv] = s2; }
    __syncthreads();
    if (p == 0) {
        float S  = red[0][0] + red[0][1] + red[0][2] + red[0][3];
        float S2 = red[1][0] + red[1][1] + red[1][2] + red[1][3];
        float mean = S / rows;
        float var  = S2 / rows - mean * mean;
        stats[c * 2]     = mean;
        stats[c * 2 + 1] = rsqrtf(var + BN_EPS);
    }
}

// ---------------------------------------------------------------- bn apply + next-layer sqnorm
template<int C>
__global__ __launch_bounds__(256) void bn_apply_sq_kernel(
        float* __restrict__ h, const float* __restrict__ stats,
        const float* __restrict__ g, const float* __restrict__ be,
        float* __restrict__ sq, int total) {
    constexpr int VPL = C / 64;
    int gw = (int)((blockIdx.x * (size_t)blockDim.x + threadIdx.x) >> 6);
    int ln = threadIdx.x & 63;
    if (gw >= total) return;
    float ssum = 0.f;
#pragma unroll
    for (int u = 0; u < VPL; ++u) {
        int c = u * 64 + ln;
        float v = h[(size_t)gw * C + c];
        v = (v - stats[c * 2]) * stats[c * 2 + 1] * g[c] + be[c];
        h[(size_t)gw * C + c] = v;
        ssum += v * v;
    }
#pragma unroll
    for (int off = 32; off > 0; off >>= 1) ssum += __shfl_down(ssum, off, 64);
    if (ln == 0) sq[gw] = ssum;
}

// ---------------------------------------------------------------- final
__global__ void final_kernel(const float* __restrict__ g3, const float* __restrict__ b3,
                             const float* __restrict__ Wc, const float* __restrict__ bc,
                             float* __restrict__ out, int total) {
    int t = blockIdx.x * blockDim.x + threadIdx.x;
    if (t >= total * 16) return;
    int o = t & 15;
    int i = t >> 4;
    float acc = bc[o];
#pragma unroll
    for (int c = 0; c < 6; ++c) {
        float hm = 0.f;
#pragma unroll
        for (int h = 0; h < 8; ++h) hm += g3[(size_t)i * 48 + h * 6 + c];
        hm = hm * 0.125f + b3[c];
        acc += hm * Wc[c * 16 + o];
    }
    out[t] = acc;
}

static inline int cdiv(int a, int b) { return (a + b - 1) / b; }

extern "C" void kernel_launch(void* const* d_in, const int* in_sizes, int n_in,
                              void* d_out, int out_size, void* d_ws, size_t ws_size,
                              hipStream_t stream) {
    const float* x    = (const float*)d_in[0];
    const float* W1   = (const float*)d_in[2];
    const float* att1 = (const float*)d_in[3];
    const float* b1   = (const float*)d_in[4];
    const float* p1   = (const float*)d_in[5];
    const float* g1   = (const float*)d_in[6];
    const float* be1  = (const float*)d_in[7];
    const float* W2   = (const float*)d_in[8];
    const float* att2 = (const float*)d_in[9];
    const float* b2   = (const float*)d_in[10];
    const float* p2   = (const float*)d_in[11];
    const float* g2   = (const float*)d_in[12];
    const float* be2  = (const float*)d_in[13];
    const float* W3   = (const float*)d_in[14];
    const float* att3 = (const float*)d_in[15];
    const float* b3   = (const float*)d_in[16];
    const float* Wc   = (const float*)d_in[17];
    const float* bc   = (const float*)d_in[18];

    const int B = 8, N = 2048, T = B * N;
    const int NBLK = 256;
    (void)n_in; (void)in_sizes; (void)out_size;

    float* ws    = (float*)d_ws;
    float* bufA  = ws;                            // T*64
    float* bufB  = bufA + (size_t)T * 64;         // T*128
    float* bufC  = bufB + (size_t)T * 128;        // T*48
    float* sd    = bufC + (size_t)T * 48;         // T*8
    float* ss    = sd   + (size_t)T * 8;          // T*8
    float* sq    = ss   + (size_t)T * 8;          // T
    float* stats = sq   + T;                      // 256
    float* part  = stats + 256;                   // NBLK*2*128
    int*   idx   = (int*)(part + (size_t)NBLK * 256); // T*33
    float* Dxw   = (float*)(idx + (size_t)T * KTOT);  // max(T*128, PB*N*N)
    float* xw    = Dxw;

    size_t fixed_words = (size_t)(Dxw - ws);
    size_t avail_words = (ws_size / 4 > fixed_words) ? (ws_size / 4 - fixed_words) : 0;
    int PB = (int)(avail_words / ((size_t)N * N));
    if (PB < 1) PB = 1;
    if (PB > B) PB = B;

    const int BS = 256;
    const int nb = N / 64;
    const int NTRI = nb * (nb + 1) / 2;

    // ================= Layer 1 (F=3 -> H=4,C=16 -> 64) =================
    sqnorm_kernel<3><<<cdiv(T, BS), BS, 0, stream>>>(x, sq, T);
    for (int b0 = 0; b0 < B; b0 += PB) {
        int pb = (b0 + PB <= B) ? PB : (B - b0);
        dist_kernel<3><<<dim3(NTRI, 1, pb), 256, 0, stream>>>(
            x + (size_t)b0 * N * 3, sq + (size_t)b0 * N, Dxw, N);
        knn_select_kernel<2048><<<pb * N / 4, 256, 0, stream>>>(Dxw, idx, b0);
    }
    linear_kernel<3, 64><<<cdiv(T * 64, BS), BS, 0, stream>>>(x, W1, xw, T);
    scores_kernel<4, 16><<<cdiv(T * 4, BS), BS, 0, stream>>>(xw, att1, sd, ss, T);
    gat_kernel<4, 16><<<cdiv(T * 64, BS), BS, 0, stream>>>(xw, sd, ss, idx, b1, p1, 0.2f, bufA, T);
    bn_partial_kernel<64><<<NBLK, 256, 0, stream>>>(bufA, part, T, NBLK);
    bn_finalize_kernel<64><<<64, 256, 0, stream>>>(part, stats, NBLK, T);
    bn_apply_sq_kernel<64><<<cdiv(T, 4), 256, 0, stream>>>(bufA, stats, g1, be1, sq, T);

    // ================= Layer 2 (F=64 -> H=2,C=64 -> 128) =================
    for (int b0 = 0; b0 < B; b0 += PB) {
        int pb = (b0 + PB <= B) ? PB : (B - b0);
        dist_mfma_kernel<64><<<dim3(NTRI, 1, pb), 256, 0, stream>>>(
            bufA + (size_t)b0 * N * 64, sq + (size_t)b0 * N, Dxw, N);
        knn_select_kernel<2048><<<pb * N / 4, 256, 0, stream>>>(Dxw, idx, b0);
    }
    linear_kernel<64, 128><<<cdiv(T * 128, BS), BS, 0, stream>>>(bufA, W2, xw, T);
    scores_kernel<2, 64><<<cdiv(T * 2, BS), BS, 0, stream>>>(xw, att2, sd, ss, T);
    gat_kernel<2, 64><<<cdiv(T * 2 * 64, BS), BS, 0, stream>>>(xw, sd, ss, idx, b2, p2, 0.2f, bufB, T);
    bn_partial_kernel<128><<<NBLK, 256, 0, stream>>>(bufB, part, T, NBLK);
    bn_finalize_kernel<128><<<128, 256, 0, stream>>>(part, stats, NBLK, T);
    bn_apply_sq_kernel<128><<<cdiv(T, 4), 256, 0, stream>>>(bufB, stats, g2, be2, sq, T);

    // ================= Layer 3 (F=128 -> H=8,C=6 -> mean -> 6) =================
    for (int b0 = 0; b0 < B; b0 += PB) {
        int pb = (b0 + PB <= B) ? PB : (B - b0);
        dist_mfma_kernel<128><<<dim3(NTRI, 1, pb), 256, 0, stream>>>(
            bufB + (size_t)b0 * N * 128, sq + (size_t)b0 * N, Dxw, N);
        knn_select_kernel<2048><<<pb * N / 4, 256, 0, stream>>>(Dxw, idx, b0);
    }
    linear_kernel<128, 48><<<cdiv(T * 48, BS), BS, 0, stream>>>(bufB, W3, xw, T);
    scores_kernel<8, 6><<<cdiv(T * 8, BS), BS, 0, stream>>>(xw, att3, sd, ss, T);
    gat_kernel<8, 6><<<cdiv(T * 64, BS), BS, 0, stream>>>(xw, sd, ss, idx, nullptr, nullptr, 0.5f, bufC, T);

    // ================= Final =================
    final_kernel<<<cdiv(T * 16, BS), BS, 0, stream>>>(bufC, b3, Wc, bc, (float*)d_out, T);
}